// Round 2
// baseline (2483.970 us; speedup 1.0000x reference)
//
#include <hip/hip_runtime.h>
#include <hip/hip_bf16.h>
#include <math.h>

#define H 256
#define AFEAT 153
#define BFEAT 14
#define KINIT 167          // AFEAT + BFEAT
#define KOUT 409           // AFEAT + H
#define NA 49152
#define NB 147456
#define NMOL 1024
#define APM 48
#define MAXNB 6
#define NHEAD 4
#define HDIM 64
#define EPSLN 1e-5f

typedef unsigned short u16;

__device__ __forceinline__ float gelu_f(float x) {
    return 0.5f * x * (1.0f + erff(x * 0.70710678118654752f));
}

__device__ __forceinline__ float wave_sum(float v) {
    #pragma unroll
    for (int m = 1; m < 64; m <<= 1) v += __shfl_xor(v, m);
    return v;
}

// bf16 (stored as u16) <-> f32 helpers. Compute stays f32 everywhere.
__device__ __forceinline__ float b2f(u16 u) {
    union { unsigned u32; float f; } c; c.u32 = ((unsigned)u) << 16; return c.f;
}
__device__ __forceinline__ float blo(unsigned w) {
    union { unsigned u; float f; } c; c.u = w << 16; return c.f;
}
__device__ __forceinline__ float bhi(unsigned w) {
    union { unsigned u; float f; } c; c.u = w & 0xffff0000u; return c.f;
}
__device__ __forceinline__ u16 f2b(float f) {        // RNE via hip intrinsic
    __hip_bfloat16 h = __float2bfloat16(f);
    u16 u; __builtin_memcpy(&u, &h, 2); return u;
}
__device__ __forceinline__ ushort4 f2b4(float a, float b, float c, float d) {
    ushort4 o; o.x = f2b(a); o.y = f2b(b); o.z = f2b(c); o.w = f2b(d); return o;
}

// ---------------- A loaders for the generic GEMM (emit f32 into LDS) ----------------
struct LoadPlainB {                 // A is bf16, row-major, ldA elements
    const u16* A; int ldA;
    __device__ __forceinline__ void load8(int row, int k0, float* v) const {
        const uint4 w = *(const uint4*)(A + (size_t)row * ldA + k0);
        v[0]=blo(w.x); v[1]=bhi(w.x); v[2]=blo(w.y); v[3]=bhi(w.y);
        v[4]=blo(w.z); v[5]=bhi(w.z); v[6]=blo(w.w); v[7]=bhi(w.w);
    }
};

struct LoadInit {  // row = bond: concat(f_atoms[b2a[row]], f_bonds[row]) (both f32), K=167
    const float* fa; const float* fb; const int* b2a;
    __device__ __forceinline__ void load8(int row, int k0, float* v) const {
        const int a = b2a[row];
        #pragma unroll
        for (int i = 0; i < 8; ++i) {
            int k = k0 + i;
            float x = 0.f;
            if (k < AFEAT) x = fa[(size_t)a * AFEAT + k];
            else if (k < KINIT) x = fb[(size_t)row * BFEAT + (k - AFEAT)];
            v[i] = x;
        }
    }
};

struct LoadCatAtom {  // row = atom: concat(f_atoms[row] (f32), a_message[row] (bf16)), K=409
    const float* fa; const u16* am;
    __device__ __forceinline__ void load8(int row, int k0, float* v) const {
        #pragma unroll
        for (int i = 0; i < 8; ++i) {
            int k = k0 + i;
            float x = 0.f;
            if (k < AFEAT) x = fa[(size_t)row * AFEAT + k];
            else if (k < KOUT) x = b2f(am[(size_t)row * H + (k - AFEAT)]);
            v[i] = x;
        }
    }
};

// ---------------- generic GEMM: C[M x N](bf16) = op(A@W + bias), W,bias f32 ----------------
// block: 64 rows x 256 cols, 256 threads, 16x4 micro-tile/thread, BK=32
template<class Loader, bool GELU, bool ACCUM>
__global__ __launch_bounds__(256) void gemm_k(
    Loader ld, const float* __restrict__ W, const float* __restrict__ bias,
    u16* __restrict__ C, int K, int N)
{
    __shared__ float As[64][36];
    __shared__ float Ws[32][260];
    const int tid = threadIdx.x;
    const int r0 = blockIdx.x * 64;
    const int c0 = blockIdx.y * 256;
    const int colq = (tid & 63) * 4;       // 4 cols per thread
    const int rq = (tid >> 6) * 16;        // 16 rows per thread (wave-uniform)

    float acc[16][4];
    #pragma unroll
    for (int i = 0; i < 16; ++i)
        #pragma unroll
        for (int j = 0; j < 4; ++j) acc[i][j] = 0.f;

    const int arow = tid >> 2;             // 0..63
    const int ak0 = (tid & 3) * 8;         // 0,8,16,24
    const int wk = tid >> 6;               // 0..3

    for (int k0 = 0; k0 < K; k0 += 32) {
        float av[8];
        ld.load8(r0 + arow, k0 + ak0, av);
        *(float4*)&As[arow][ak0]     = make_float4(av[0],av[1],av[2],av[3]);
        *(float4*)&As[arow][ak0 + 4] = make_float4(av[4],av[5],av[6],av[7]);
        #pragma unroll
        for (int i = 0; i < 8; ++i) {
            int k = k0 + wk + i * 4;
            float4 w = make_float4(0,0,0,0);
            if (k < K) w = *(const float4*)&W[(size_t)k * N + c0 + colq];
            *(float4*)&Ws[wk + i*4][colq] = w;
        }
        __syncthreads();
        #pragma unroll
        for (int kk = 0; kk < 32; kk += 4) {
            float4 w0 = *(const float4*)&Ws[kk  ][colq];
            float4 w1 = *(const float4*)&Ws[kk+1][colq];
            float4 w2 = *(const float4*)&Ws[kk+2][colq];
            float4 w3 = *(const float4*)&Ws[kk+3][colq];
            #pragma unroll
            for (int rr = 0; rr < 16; ++rr) {
                float4 a = *(const float4*)&As[rq + rr][kk];
                acc[rr][0] += a.x*w0.x; acc[rr][1] += a.x*w0.y; acc[rr][2] += a.x*w0.z; acc[rr][3] += a.x*w0.w;
                acc[rr][0] += a.y*w1.x; acc[rr][1] += a.y*w1.y; acc[rr][2] += a.y*w1.z; acc[rr][3] += a.y*w1.w;
                acc[rr][0] += a.z*w2.x; acc[rr][1] += a.z*w2.y; acc[rr][2] += a.z*w2.z; acc[rr][3] += a.z*w2.w;
                acc[rr][0] += a.w*w3.x; acc[rr][1] += a.w*w3.y; acc[rr][2] += a.w*w3.z; acc[rr][3] += a.w*w3.w;
            }
        }
        __syncthreads();
    }
    float4 bi = *(const float4*)&bias[c0 + colq];
    #pragma unroll
    for (int rr = 0; rr < 16; ++rr) {
        int r = r0 + rq + rr;
        float vx = acc[rr][0] + bi.x, vy = acc[rr][1] + bi.y;
        float vz = acc[rr][2] + bi.z, vw = acc[rr][3] + bi.w;
        if (GELU) { vx = gelu_f(vx); vy = gelu_f(vy); vz = gelu_f(vz); vw = gelu_f(vw); }
        u16* cp = &C[(size_t)r * N + c0 + colq];
        if (ACCUM) {
            ushort4 o = *(const ushort4*)cp;
            vx += b2f(o.x); vy += b2f(o.y); vz += b2f(o.z); vw += b2f(o.w);
        }
        *(ushort4*)cp = f2b4(vx, vy, vz, vw);
    }
}

// ---------------- gather-sum over incoming bonds: nei[a] = sum_j msg[a2b[a,j]] ----------------
__global__ __launch_bounds__(256) void nei_sum_k(const u16* __restrict__ msg,
    const int* __restrict__ a2b, u16* __restrict__ nei)
{
    const int wave = threadIdx.x >> 6;
    const int lane = threadIdx.x & 63;
    const int atom = blockIdx.x * 4 + wave;
    float ax=0.f, ay=0.f, az=0.f, aw=0.f;
    #pragma unroll
    for (int j = 0; j < MAXNB; ++j) {
        int b = a2b[atom * MAXNB + j];
        ushort4 v = *(const ushort4*)(msg + (size_t)b * H + lane * 4);
        ax += b2f(v.x); ay += b2f(v.y); az += b2f(v.z); aw += b2f(v.w);
    }
    *(ushort4*)(nei + (size_t)atom * H + lane * 4) = f2b4(ax, ay, az, aw);
}

// ---------------- per-bond: normed = LN(nei[b2a[b]] - msg[b2revb[b]])*s + b ----------------
__global__ __launch_bounds__(256) void bond_ln_k(const u16* __restrict__ nei,
    const u16* __restrict__ msg, const int* __restrict__ b2a,
    const int* __restrict__ b2revb, const float* __restrict__ s,
    const float* __restrict__ b, u16* __restrict__ out)
{
    const int wave = threadIdx.x >> 6;
    const int lane = threadIdx.x & 63;
    const int bond = blockIdx.x * 4 + wave;
    const int a = b2a[bond];
    const int rb = b2revb[bond];
    ushort4 un = *(const ushort4*)(nei + (size_t)a * H + lane * 4);
    ushort4 um = *(const ushort4*)(msg + (size_t)rb * H + lane * 4);
    float vx = b2f(un.x) - b2f(um.x), vy = b2f(un.y) - b2f(um.y);
    float vz = b2f(un.z) - b2f(um.z), vw = b2f(un.w) - b2f(um.w);
    float mean = wave_sum(vx + vy + vz + vw) * (1.0f / H);
    float dx = vx-mean, dy = vy-mean, dz = vz-mean, dw = vw-mean;
    float var = wave_sum(dx*dx + dy*dy + dz*dz + dw*dw) * (1.0f / H);
    float inv = rsqrtf(var + EPSLN);
    float4 s4 = *(const float4*)(s + lane * 4);
    float4 b4 = *(const float4*)(b + lane * 4);
    *(ushort4*)(out + (size_t)bond * H + lane * 4) =
        f2b4(dx*inv*s4.x + b4.x, dy*inv*s4.y + b4.y, dz*inv*s4.z + b4.z, dw*inv*s4.w + b4.w);
}

// ---------------- per-row LN over H=256 ----------------
__global__ __launch_bounds__(256) void row_ln_k(const u16* __restrict__ in,
    u16* __restrict__ out, const float* __restrict__ s, const float* __restrict__ b)
{
    const int wave = threadIdx.x >> 6;
    const int lane = threadIdx.x & 63;
    const int row = blockIdx.x * 4 + wave;
    ushort4 u = *(const ushort4*)(in + (size_t)row * H + lane * 4);
    float vx = b2f(u.x), vy = b2f(u.y), vz = b2f(u.z), vw = b2f(u.w);
    float mean = wave_sum(vx + vy + vz + vw) * (1.0f / H);
    float dx = vx-mean, dy = vy-mean, dz = vz-mean, dw = vw-mean;
    float var = wave_sum(dx*dx + dy*dy + dz*dz + dw*dw) * (1.0f / H);
    float inv = rsqrtf(var + EPSLN);
    float4 s4 = *(const float4*)(s + lane * 4);
    float4 b4 = *(const float4*)(b + lane * 4);
    *(ushort4*)(out + (size_t)row * H + lane * 4) =
        f2b4(dx*inv*s4.x + b4.x, dy*inv*s4.y + b4.y, dz*inv*s4.z + b4.z, dw*inv*s4.w + b4.w);
}

// ---------------- attention per (mol, head): 48x48 softmax(QK^T/8) @ V ----------------
__global__ __launch_bounds__(256) void attn_k(const u16* __restrict__ q,
    const u16* __restrict__ k, const u16* __restrict__ v, u16* __restrict__ ctx)
{
    __shared__ float qs[48][68], ks[48][68], vs[48][68], sc[48][52];
    const int mol = blockIdx.x >> 2;
    const int head = blockIdx.x & 3;
    const int tid = threadIdx.x;
    const size_t base = (size_t)mol * APM * H + head * HDIM;
    #pragma unroll
    for (int i = 0; i < 3; ++i) {
        int slot = tid + i * 256;          // 0..767 -> (s, d4)
        int s = slot >> 4, d4 = (slot & 15) * 4;
        ushort4 uq = *(const ushort4*)(q + base + (size_t)s * H + d4);
        ushort4 uk = *(const ushort4*)(k + base + (size_t)s * H + d4);
        ushort4 uv = *(const ushort4*)(v + base + (size_t)s * H + d4);
        qs[s][d4]=b2f(uq.x); qs[s][d4+1]=b2f(uq.y); qs[s][d4+2]=b2f(uq.z); qs[s][d4+3]=b2f(uq.w);
        ks[s][d4]=b2f(uk.x); ks[s][d4+1]=b2f(uk.y); ks[s][d4+2]=b2f(uk.z); ks[s][d4+3]=b2f(uk.w);
        vs[s][d4]=b2f(uv.x); vs[s][d4+1]=b2f(uv.y); vs[s][d4+2]=b2f(uv.z); vs[s][d4+3]=b2f(uv.w);
    }
    __syncthreads();
    #pragma unroll
    for (int i = 0; i < 9; ++i) {
        int e = tid + i * 256;             // 0..2303
        int qr = e / 48, kr = e % 48;
        float acc = 0.f;
        #pragma unroll
        for (int d = 0; d < 64; d += 4) {
            float4 a = *(const float4*)&qs[qr][d];
            float4 bb = *(const float4*)&ks[kr][d];
            acc += a.x*bb.x + a.y*bb.y + a.z*bb.z + a.w*bb.w;
        }
        sc[qr][kr] = acc * 0.125f;
    }
    __syncthreads();
    if (tid < 48) {
        float mx = -1e30f;
        for (int j = 0; j < 48; ++j) mx = fmaxf(mx, sc[tid][j]);
        float sum = 0.f;
        for (int j = 0; j < 48; ++j) { float e = expf(sc[tid][j] - mx); sc[tid][j] = e; sum += e; }
        float inv = 1.0f / sum;
        for (int j = 0; j < 48; ++j) sc[tid][j] *= inv;
    }
    __syncthreads();
    #pragma unroll
    for (int i = 0; i < 3; ++i) {
        int slot = tid + i * 256;
        int s = slot >> 4, d4 = (slot & 15) * 4;
        float ax=0.f, ay=0.f, az=0.f, aw=0.f;
        for (int j = 0; j < 48; ++j) {
            float w = sc[s][j];
            float4 vv = *(const float4*)&vs[j][d4];
            ax += w*vv.x; ay += w*vv.y; az += w*vv.z; aw += w*vv.w;
        }
        *(ushort4*)(ctx + base + (size_t)s * H + d4) = f2b4(ax, ay, az, aw);
    }
}

// ---------------- readout prep: rv = rk_w @ query, c0 = rk_b . query (all f32 in) ----------------
__global__ __launch_bounds__(256) void readout_prep_k(const float* __restrict__ rk_w,
    const float* __restrict__ rk_b, const float* __restrict__ query, float* __restrict__ small)
{
    __shared__ float qsh[256];
    __shared__ float red[4];
    const int t = threadIdx.x;
    qsh[t] = query[t];
    __syncthreads();
    float acc = 0.f;
    #pragma unroll
    for (int c = 0; c < 256; c += 4) {
        float4 w = *(const float4*)&rk_w[(size_t)t * 256 + c];
        acc += w.x*qsh[c] + w.y*qsh[c+1] + w.z*qsh[c+2] + w.w*qsh[c+3];
    }
    small[t] = acc;
    float term = wave_sum(rk_b[t] * qsh[t]);
    if ((t & 63) == 0) red[t >> 6] = term;
    __syncthreads();
    if (t == 0) small[256] = red[0] + red[1] + red[2] + red[3];
}

// ---------------- readout: softmax(x . rv + c0) weighted sum over 48 atoms ----------------
__global__ __launch_bounds__(256) void readout_k(const u16* __restrict__ x,
    const float* __restrict__ small, float* __restrict__ out)
{
    __shared__ float sc[48];
    __shared__ float rvs[256];
    const int mol = blockIdx.x;
    const int t = threadIdx.x;
    const int wave = t >> 6, lane = t & 63;
    rvs[t] = small[t];
    __syncthreads();
    const float c0 = small[256];
    const size_t xb = (size_t)mol * APM * H;
    for (int i = 0; i < 12; ++i) {
        int s = wave * 12 + i;
        ushort4 xu = *(const ushort4*)(x + xb + (size_t)s * H + lane * 4);
        float dot = b2f(xu.x)*rvs[lane*4] + b2f(xu.y)*rvs[lane*4+1]
                  + b2f(xu.z)*rvs[lane*4+2] + b2f(xu.w)*rvs[lane*4+3];
        dot = wave_sum(dot);
        if (lane == 0) sc[s] = dot + c0;
    }
    __syncthreads();
    if (wave == 0) {
        float v = (lane < 48) ? sc[lane] : -1e30f;
        float mx = v;
        #pragma unroll
        for (int m = 1; m < 64; m <<= 1) mx = fmaxf(mx, __shfl_xor(mx, m));
        float e = (lane < 48) ? expf(v - mx) : 0.f;
        float sum = wave_sum(e);
        if (lane < 48) sc[lane] = e / sum;
    }
    __syncthreads();
    float acc = 0.f;
    for (int s = 0; s < 48; ++s) acc += sc[s] * b2f(x[xb + (size_t)s * H + t]);
    out[(size_t)mol * H + t] = acc;
}

// diagnostic: encode ws_size (MiB) into absmax if workspace is too small
__global__ void diag_k(float* out, int n, float val) {
    int i = blockIdx.x * 256 + threadIdx.x;
    if (i < n) out[i] = (i == 0) ? val : 0.f;
}

extern "C" void kernel_launch(void* const* d_in, const int* in_sizes, int n_in,
                              void* d_out, int out_size, void* d_ws, size_t ws_size,
                              hipStream_t stream)
{
    const float* f_atoms = (const float*)d_in[0];
    const float* f_bonds = (const float*)d_in[1];
    const int*   a2b     = (const int*)d_in[2];
    const int*   b2a     = (const int*)d_in[3];
    const int*   b2revb  = (const int*)d_in[4];
    const float* W_i = (const float*)d_in[5];
    const float* b_i = (const float*)d_in[6];
    const float* W_h = (const float*)d_in[7];
    const float* b_h = (const float*)d_in[8];
    const float* ln_msg_s = (const float*)d_in[9];
    const float* ln_msg_b = (const float*)d_in[10];
    const float* W_o = (const float*)d_in[11];
    const float* b_o = (const float*)d_in[12];
    const float* ln_atom_s = (const float*)d_in[13];
    const float* ln_atom_b = (const float*)d_in[14];
    const float* q_w = (const float*)d_in[15];
    const float* q_b = (const float*)d_in[16];
    const float* k_w = (const float*)d_in[17];
    const float* k_b = (const float*)d_in[18];
    const float* v_w = (const float*)d_in[19];
    const float* v_b = (const float*)d_in[20];
    const float* o_w = (const float*)d_in[21];
    const float* o_b = (const float*)d_in[22];
    const float* ln1_s = (const float*)d_in[23];
    const float* ln1_b = (const float*)d_in[24];
    const float* ln2_s = (const float*)d_in[25];
    const float* ln2_b = (const float*)d_in[26];
    const float* ff1_w = (const float*)d_in[27];
    const float* ff1_b = (const float*)d_in[28];
    const float* ff2_w = (const float*)d_in[29];
    const float* ff2_b = (const float*)d_in[30];
    const float* rquery = (const float*)d_in[31];
    const float* rk_w = (const float*)d_in[32];
    const float* rk_b = (const float*)d_in[33];

    // workspace: all big intermediates in bf16.  (2*NB + NA)*H*2B ~= 168 MiB
    const size_t required = ((size_t)(2 * (size_t)NB + NA) * H) * 2 + 4096;
    if (ws_size < required) {   // diagnostic: absmax will read ~ws_size in MiB
        diag_k<<<dim3((out_size + 255) / 256), dim3(256), 0, stream>>>(
            (float*)d_out, out_size, (float)(ws_size >> 20));
        return;
    }

    u16* msg    = (u16*)d_ws;                            // NB*H
    u16* normed = msg + (size_t)NB * H;                  // NB*H
    u16* nei    = normed + (size_t)NB * H;               // NA*H
    float* small = (float*)(nei + (size_t)NA * H);       // 257 f32
    // post-message-passing aliases (liveness-checked)
    u16* x    = msg;                                     // NA*H
    u16* h    = msg + (size_t)NA * H;                    // NA*H (dead after q/k/v)
    u16* ff1o = msg + (size_t)NA * H;                    // NA*512, ends at msg+NB*H
    u16* qb_  = normed;
    u16* kb_  = normed + (size_t)NA * H;
    u16* vb_  = normed + (size_t)2 * NA * H;
    u16* ctx  = nei;
    u16* h2   = nei;                                     // after ctx dead
    float* out = (float*)d_out;

    dim3 blk(256);

    // 1. message init: gelu(concat(f_atoms[b2a], f_bonds) @ W_i + b_i)
    gemm_k<LoadInit, true, false><<<dim3(NB/64, 1), blk, 0, stream>>>(
        LoadInit{f_atoms, f_bonds, b2a}, W_i, b_i, msg, KINIT, H);

    // 2. depth loop
    for (int t = 0; t < 3; ++t) {
        nei_sum_k<<<dim3(NA/4), blk, 0, stream>>>(msg, a2b, nei);
        bond_ln_k<<<dim3(NB/4), blk, 0, stream>>>(nei, msg, b2a, b2revb,
            ln_msg_s + t*H, ln_msg_b + t*H, normed);
        gemm_k<LoadPlainB, true, true><<<dim3(NB/64, 1), blk, 0, stream>>>(
            LoadPlainB{normed, H}, W_h + (size_t)t*H*H, b_h + t*H, msg, H, H);
    }

    // 3. atom hidden: a_message, gelu(concat(f_atoms, a_message) @ W_o + b_o), LN
    nei_sum_k<<<dim3(NA/4), blk, 0, stream>>>(msg, a2b, nei);
    gemm_k<LoadCatAtom, true, false><<<dim3(NA/64, 1), blk, 0, stream>>>(
        LoadCatAtom{f_atoms, nei}, W_o, b_o, x, KOUT, H);
    row_ln_k<<<dim3(NA/4), blk, 0, stream>>>(x, x, ln_atom_s, ln_atom_b);

    // 4. transformer layer (pre-norm)
    row_ln_k<<<dim3(NA/4), blk, 0, stream>>>(x, h, ln1_s, ln1_b);
    gemm_k<LoadPlainB, false, false><<<dim3(NA/64, 1), blk, 0, stream>>>(
        LoadPlainB{h, H}, q_w, q_b, qb_, H, H);
    gemm_k<LoadPlainB, false, false><<<dim3(NA/64, 1), blk, 0, stream>>>(
        LoadPlainB{h, H}, k_w, k_b, kb_, H, H);
    gemm_k<LoadPlainB, false, false><<<dim3(NA/64, 1), blk, 0, stream>>>(
        LoadPlainB{h, H}, v_w, v_b, vb_, H, H);
    attn_k<<<dim3(NMOL*NHEAD), blk, 0, stream>>>(qb_, kb_, vb_, ctx);
    gemm_k<LoadPlainB, false, true><<<dim3(NA/64, 1), blk, 0, stream>>>(
        LoadPlainB{ctx, H}, o_w, o_b, x, H, H);
    row_ln_k<<<dim3(NA/4), blk, 0, stream>>>(x, h2, ln2_s, ln2_b);
    gemm_k<LoadPlainB, true, false><<<dim3(NA/64, 2), blk, 0, stream>>>(
        LoadPlainB{h2, H}, ff1_w, ff1_b, ff1o, H, 512);
    gemm_k<LoadPlainB, false, true><<<dim3(NA/64, 1), blk, 0, stream>>>(
        LoadPlainB{ff1o, 512}, ff2_w, ff2_b, x, 512, H);

    // 5. readout (algebraic: scores = x.(rk_w@q) + rk_b.q)
    readout_prep_k<<<dim3(1), blk, 0, stream>>>(rk_w, rk_b, rquery, small);
    readout_k<<<dim3(NMOL), blk, 0, stream>>>(x, small, out);
}

// Round 3
// 925.405 us; speedup vs baseline: 2.6842x; 2.6842x over previous
//
#include <hip/hip_runtime.h>
#include <hip/hip_bf16.h>
#include <math.h>

#define H 256
#define AFEAT 153
#define BFEAT 14
#define KINIT 167
#define NA 49152
#define NB 147456
#define NMOL 1024
#define APM 48
#define MAXNB 6
#define NHEAD 4
#define HDIM 64
#define EPSLN 1e-5f
#define KI_PAD 192          // init GEMM K padded (mult of 64)
#define KO_PAD 448          // W_o GEMM K padded (153+256=409 -> 448)

typedef unsigned short u16;
typedef __attribute__((ext_vector_type(8))) short bf16x8;
typedef __attribute__((ext_vector_type(4))) float f32x4;

__device__ __forceinline__ float gelu_f(float x) {
    return 0.5f * x * (1.0f + erff(x * 0.70710678118654752f));
}
__device__ __forceinline__ float wave_sum(float v) {
    #pragma unroll
    for (int m = 1; m < 64; m <<= 1) v += __shfl_xor(v, m);
    return v;
}
__device__ __forceinline__ float b2f(u16 u) {
    union { unsigned u32; float f; } c; c.u32 = ((unsigned)u) << 16; return c.f;
}
__device__ __forceinline__ u16 f2b(float f) {
    __hip_bfloat16 h = __float2bfloat16(f);
    u16 u; __builtin_memcpy(&u, &h, 2); return u;
}
__device__ __forceinline__ ushort4 f2b4(float a, float b, float c, float d) {
    ushort4 o; o.x = f2b(a); o.y = f2b(b); o.z = f2b(c); o.w = f2b(d); return o;
}

// async global->LDS, 16B per lane, dest = wave-uniform base + lane*16
typedef const __attribute__((address_space(1))) void* gas_ptr;
typedef __attribute__((address_space(3))) void* las_ptr;
__device__ __forceinline__ void gload_lds16(const u16* g, u16* l) {
    __builtin_amdgcn_global_load_lds((gas_ptr)g, (las_ptr)l, 16, 0, 0);
}

// ================= MFMA GEMM: C[M][Nc] = op(A @ Wt^T + bias) =================
// A bf16 [M][Ka], Wt bf16 [Ntot][Ka] (pre-transposed weights), K = Ka (mult 64).
// Block: 256 thr (4 waves), tile 128x128, BK=64. LDS XOR-swizzle (row&7)<<4.
template<bool GELU, bool ACCUM>
__global__ __launch_bounds__(256) void gemm_mfma_k(
    const u16* __restrict__ A, int Ka,
    const u16* __restrict__ Wt,
    const float* __restrict__ bias,
    u16* __restrict__ C, int Nc, int K)
{
    __shared__ __align__(16) u16 As[128 * 64];
    __shared__ __align__(16) u16 Bs[128 * 64];
    const int tid = threadIdx.x;
    const int w = tid >> 6, l = tid & 63;
    const int r0 = blockIdx.x * 128;
    const int cb0 = blockIdx.y * 128;
    const int wr = (w >> 1) * 64;      // wave row offset in tile
    const int wc = (w & 1) * 64;       // wave col offset in tile

    f32x4 acc[4][4];
    #pragma unroll
    for (int m = 0; m < 4; ++m)
        #pragma unroll
        for (int n = 0; n < 4; ++n) acc[m][n] = (f32x4){0.f, 0.f, 0.f, 0.f};

    // staging: seg = w*4+i covers 8 rows (1KB). lane -> row l>>3, 16B slot l&7.
    const int srow = l >> 3;                   // 0..7  (== row & 7)
    const int sslot = (l & 7) * 16;            // byte slot
    const int ssrc = sslot ^ (srow << 4);      // pre-swizzled source byte offset

    const int fr = l & 15;                     // fragment row/col index
    const int fh = l >> 4;                     // 0..3
    const int swz = (fr & 7) << 4;

    for (int k0 = 0; k0 < K; k0 += 64) {
        #pragma unroll
        for (int i = 0; i < 4; ++i) {
            const int seg = w * 4 + i;
            gload_lds16(A + (size_t)(r0 + seg * 8 + srow) * Ka + k0 + (ssrc >> 1),
                        &As[seg * 512]);
            gload_lds16(Wt + (size_t)(cb0 + seg * 8 + srow) * Ka + k0 + (ssrc >> 1),
                        &Bs[seg * 512]);
        }
        __syncthreads();
        #pragma unroll
        for (int s = 0; s < 2; ++s) {
            const int cbyte = ((s * 64 + fh * 16) ^ swz) >> 1;   // u16 offset in row
            bf16x8 af[4], bv[4];
            #pragma unroll
            for (int m = 0; m < 4; ++m)
                af[m] = *(const bf16x8*)&As[(wr + m * 16 + fr) * 64 + cbyte];
            #pragma unroll
            for (int n = 0; n < 4; ++n)
                bv[n] = *(const bf16x8*)&Bs[(wc + n * 16 + fr) * 64 + cbyte];
            #pragma unroll
            for (int m = 0; m < 4; ++m)
                #pragma unroll
                for (int n = 0; n < 4; ++n)
                    acc[m][n] = __builtin_amdgcn_mfma_f32_16x16x32_bf16(
                        af[m], bv[n], acc[m][n], 0, 0, 0);
        }
        __syncthreads();
    }

    // epilogue: C/D frag layout col=lane&15, row=(lane>>4)*4+reg  [measured]
    float bvv[4];
    #pragma unroll
    for (int n = 0; n < 4; ++n) bvv[n] = bias[cb0 + wc + n * 16 + fr];
    #pragma unroll
    for (int m = 0; m < 4; ++m) {
        #pragma unroll
        for (int n = 0; n < 4; ++n) {
            const int col = cb0 + wc + n * 16 + fr;
            #pragma unroll
            for (int j = 0; j < 4; ++j) {
                const int row = r0 + wr + m * 16 + fh * 4 + j;
                float v = acc[m][n][j] + bvv[n];
                if (GELU) v = gelu_f(v);
                u16* p = &C[(size_t)row * Nc + col];
                if (ACCUM) v += b2f(*p);
                *p = f2b(v);
            }
        }
    }
}

// ============ weight convert+transpose: W f32[K][N] -> Wt bf16[N][Kpad] ============
__global__ __launch_bounds__(256) void wcvt_k(const float* __restrict__ W,
    u16* __restrict__ Wt, int K, int N, int Kpad)
{
    int idx = blockIdx.x * 256 + threadIdx.x;
    if (idx >= N * Kpad) return;
    int n = idx / Kpad, kp = idx - n * Kpad;
    Wt[idx] = (kp < K) ? f2b(W[(size_t)kp * N + n]) : (u16)0;
}

__global__ void biaspack_k(const float* q, const float* k, const float* v, float* dst) {
    int t = threadIdx.x;
    dst[t] = q[t]; dst[256 + t] = k[t]; dst[512 + t] = v[t];
}

// ============ materialize A_init bf16 [NB][192]: concat(f_atoms[b2a], f_bonds) ============
__global__ __launch_bounds__(256) void ainit_k(const float* __restrict__ fa,
    const float* __restrict__ fb, const int* __restrict__ b2a, u16* __restrict__ dst)
{
    const int w = threadIdx.x >> 6, l = threadIdx.x & 63;
    const int row = blockIdx.x * 4 + w;
    const int a = b2a[row];
    const float* fsrc = fa + (size_t)a * AFEAT;
    u16* d = dst + (size_t)row * KI_PAD;
    #pragma unroll
    for (int i = 0; i < 3; ++i) {
        int c = l + i * 64;
        float v;
        if (c < AFEAT) v = fsrc[c];
        else if (c < KINIT) v = fb[(size_t)row * BFEAT + (c - AFEAT)];
        else v = 0.f;
        d[c] = f2b(v);
    }
}

// ============ materialize A_cat bf16 [NA][448]: concat(f_atoms, a_message) ============
__global__ __launch_bounds__(256) void acat_k(const float* __restrict__ fa,
    const u16* __restrict__ nei, u16* __restrict__ dst)
{
    const int w = threadIdx.x >> 6, l = threadIdx.x & 63;
    const int row = blockIdx.x * 4 + w;
    const float* fsrc = fa + (size_t)row * AFEAT;
    const u16* nsrc = nei + (size_t)row * H;
    u16* d = dst + (size_t)row * KO_PAD;
    #pragma unroll
    for (int i = 0; i < 7; ++i) {
        int c = l + i * 64;
        u16 v;
        if (c < AFEAT) v = f2b(fsrc[c]);
        else if (c < AFEAT + H) v = nsrc[c - AFEAT];
        else v = 0;
        d[c] = v;
    }
}

// ---------------- gather-sum: nei[a] = sum_j msg[a2b[a,j]] ----------------
__global__ __launch_bounds__(256) void nei_sum_k(const u16* __restrict__ msg,
    const int* __restrict__ a2b, u16* __restrict__ nei)
{
    const int wave = threadIdx.x >> 6;
    const int lane = threadIdx.x & 63;
    const int atom = blockIdx.x * 4 + wave;
    float ax = 0.f, ay = 0.f, az = 0.f, aw = 0.f;
    #pragma unroll
    for (int j = 0; j < MAXNB; ++j) {
        int b = a2b[atom * MAXNB + j];
        ushort4 v = *(const ushort4*)(msg + (size_t)b * H + lane * 4);
        ax += b2f(v.x); ay += b2f(v.y); az += b2f(v.z); aw += b2f(v.w);
    }
    *(ushort4*)(nei + (size_t)atom * H + lane * 4) = f2b4(ax, ay, az, aw);
}

// ---------------- per-bond LN of (nei[b2a] - msg[b2revb]) ----------------
__global__ __launch_bounds__(256) void bond_ln_k(const u16* __restrict__ nei,
    const u16* __restrict__ msg, const int* __restrict__ b2a,
    const int* __restrict__ b2revb, const float* __restrict__ s,
    const float* __restrict__ b, u16* __restrict__ out)
{
    const int wave = threadIdx.x >> 6;
    const int lane = threadIdx.x & 63;
    const int bond = blockIdx.x * 4 + wave;
    const int a = b2a[bond];
    const int rb = b2revb[bond];
    ushort4 un = *(const ushort4*)(nei + (size_t)a * H + lane * 4);
    ushort4 um = *(const ushort4*)(msg + (size_t)rb * H + lane * 4);
    float vx = b2f(un.x) - b2f(um.x), vy = b2f(un.y) - b2f(um.y);
    float vz = b2f(un.z) - b2f(um.z), vw = b2f(un.w) - b2f(um.w);
    float mean = wave_sum(vx + vy + vz + vw) * (1.0f / H);
    float dx = vx - mean, dy = vy - mean, dz = vz - mean, dw = vw - mean;
    float var = wave_sum(dx * dx + dy * dy + dz * dz + dw * dw) * (1.0f / H);
    float inv = rsqrtf(var + EPSLN);
    float4 s4 = *(const float4*)(s + lane * 4);
    float4 b4 = *(const float4*)(b + lane * 4);
    *(ushort4*)(out + (size_t)bond * H + lane * 4) =
        f2b4(dx * inv * s4.x + b4.x, dy * inv * s4.y + b4.y,
             dz * inv * s4.z + b4.z, dw * inv * s4.w + b4.w);
}

// ---------------- per-row LN over H=256 ----------------
__global__ __launch_bounds__(256) void row_ln_k(const u16* __restrict__ in,
    u16* __restrict__ out, const float* __restrict__ s, const float* __restrict__ b)
{
    const int wave = threadIdx.x >> 6;
    const int lane = threadIdx.x & 63;
    const int row = blockIdx.x * 4 + wave;
    ushort4 u = *(const ushort4*)(in + (size_t)row * H + lane * 4);
    float vx = b2f(u.x), vy = b2f(u.y), vz = b2f(u.z), vw = b2f(u.w);
    float mean = wave_sum(vx + vy + vz + vw) * (1.0f / H);
    float dx = vx - mean, dy = vy - mean, dz = vz - mean, dw = vw - mean;
    float var = wave_sum(dx * dx + dy * dy + dz * dz + dw * dw) * (1.0f / H);
    float inv = rsqrtf(var + EPSLN);
    float4 s4 = *(const float4*)(s + lane * 4);
    float4 b4 = *(const float4*)(b + lane * 4);
    *(ushort4*)(out + (size_t)row * H + lane * 4) =
        f2b4(dx * inv * s4.x + b4.x, dy * inv * s4.y + b4.y,
             dz * inv * s4.z + b4.z, dw * inv * s4.w + b4.w);
}

// ---------------- attention per (mol, head), qkv packed [NA][768] ----------------
__global__ __launch_bounds__(256) void attn_k(const u16* __restrict__ qkv,
    u16* __restrict__ ctx)
{
    __shared__ float qs[48][68], ks[48][68], vs[48][68], sc[48][52];
    const int mol = blockIdx.x >> 2;
    const int head = blockIdx.x & 3;
    const int tid = threadIdx.x;
    const size_t bq = (size_t)mol * APM * 768 + head * HDIM;
    #pragma unroll
    for (int i = 0; i < 3; ++i) {
        int slot = tid + i * 256;
        int s = slot >> 4, d4 = (slot & 15) * 4;
        ushort4 uq = *(const ushort4*)(qkv + bq + (size_t)s * 768 + d4);
        ushort4 uk = *(const ushort4*)(qkv + bq + (size_t)s * 768 + 256 + d4);
        ushort4 uv = *(const ushort4*)(qkv + bq + (size_t)s * 768 + 512 + d4);
        qs[s][d4] = b2f(uq.x); qs[s][d4+1] = b2f(uq.y); qs[s][d4+2] = b2f(uq.z); qs[s][d4+3] = b2f(uq.w);
        ks[s][d4] = b2f(uk.x); ks[s][d4+1] = b2f(uk.y); ks[s][d4+2] = b2f(uk.z); ks[s][d4+3] = b2f(uk.w);
        vs[s][d4] = b2f(uv.x); vs[s][d4+1] = b2f(uv.y); vs[s][d4+2] = b2f(uv.z); vs[s][d4+3] = b2f(uv.w);
    }
    __syncthreads();
    #pragma unroll
    for (int i = 0; i < 9; ++i) {
        int e = tid + i * 256;
        int qr = e / 48, kr = e % 48;
        float acc = 0.f;
        #pragma unroll
        for (int d = 0; d < 64; d += 4) {
            float4 a = *(const float4*)&qs[qr][d];
            float4 bb = *(const float4*)&ks[kr][d];
            acc += a.x * bb.x + a.y * bb.y + a.z * bb.z + a.w * bb.w;
        }
        sc[qr][kr] = acc * 0.125f;
    }
    __syncthreads();
    if (tid < 48) {
        float mx = -1e30f;
        for (int j = 0; j < 48; ++j) mx = fmaxf(mx, sc[tid][j]);
        float sum = 0.f;
        for (int j = 0; j < 48; ++j) { float e = expf(sc[tid][j] - mx); sc[tid][j] = e; sum += e; }
        float inv = 1.0f / sum;
        for (int j = 0; j < 48; ++j) sc[tid][j] *= inv;
    }
    __syncthreads();
    const size_t bc = (size_t)mol * APM * H + head * HDIM;
    #pragma unroll
    for (int i = 0; i < 3; ++i) {
        int slot = tid + i * 256;
        int s = slot >> 4, d4 = (slot & 15) * 4;
        float ax = 0.f, ay = 0.f, az = 0.f, aw = 0.f;
        for (int j = 0; j < 48; ++j) {
            float w = sc[s][j];
            float4 vv = *(const float4*)&vs[j][d4];
            ax += w * vv.x; ay += w * vv.y; az += w * vv.z; aw += w * vv.w;
        }
        *(ushort4*)(ctx + bc + (size_t)s * H + d4) = f2b4(ax, ay, az, aw);
    }
}

// ---------------- readout prep: rv = rk_w @ query, c0 = rk_b . query ----------------
__global__ __launch_bounds__(256) void readout_prep_k(const float* __restrict__ rk_w,
    const float* __restrict__ rk_b, const float* __restrict__ query, float* __restrict__ small)
{
    __shared__ float qsh[256];
    __shared__ float red[4];
    const int t = threadIdx.x;
    qsh[t] = query[t];
    __syncthreads();
    float acc = 0.f;
    #pragma unroll
    for (int c = 0; c < 256; c += 4) {
        float4 w = *(const float4*)&rk_w[(size_t)t * 256 + c];
        acc += w.x * qsh[c] + w.y * qsh[c+1] + w.z * qsh[c+2] + w.w * qsh[c+3];
    }
    small[t] = acc;
    float term = wave_sum(rk_b[t] * qsh[t]);
    if ((t & 63) == 0) red[t >> 6] = term;
    __syncthreads();
    if (t == 0) small[256] = red[0] + red[1] + red[2] + red[3];
}

// ---------------- readout ----------------
__global__ __launch_bounds__(256) void readout_k(const u16* __restrict__ x,
    const float* __restrict__ small, float* __restrict__ out)
{
    __shared__ float sc[48];
    __shared__ float rvs[256];
    const int mol = blockIdx.x;
    const int t = threadIdx.x;
    const int wave = t >> 6, lane = t & 63;
    rvs[t] = small[t];
    __syncthreads();
    const float c0 = small[256];
    const size_t xb = (size_t)mol * APM * H;
    for (int i = 0; i < 12; ++i) {
        int s = wave * 12 + i;
        ushort4 xu = *(const ushort4*)(x + xb + (size_t)s * H + lane * 4);
        float dot = b2f(xu.x) * rvs[lane*4] + b2f(xu.y) * rvs[lane*4+1]
                  + b2f(xu.z) * rvs[lane*4+2] + b2f(xu.w) * rvs[lane*4+3];
        dot = wave_sum(dot);
        if (lane == 0) sc[s] = dot + c0;
    }
    __syncthreads();
    if (wave == 0) {
        float v = (lane < 48) ? sc[lane] : -1e30f;
        float mx = v;
        #pragma unroll
        for (int m = 1; m < 64; m <<= 1) mx = fmaxf(mx, __shfl_xor(mx, m));
        float e = (lane < 48) ? expf(v - mx) : 0.f;
        float sum = wave_sum(e);
        if (lane < 48) sc[lane] = e / sum;
    }
    __syncthreads();
    float acc = 0.f;
    for (int s = 0; s < 48; ++s) acc += sc[s] * b2f(x[xb + (size_t)s * H + t]);
    out[(size_t)mol * H + t] = acc;
}

__global__ void diag_k(float* out, int n, float val) {
    int i = blockIdx.x * 256 + threadIdx.x;
    if (i < n) out[i] = (i == 0) ? val : 0.f;
}

extern "C" void kernel_launch(void* const* d_in, const int* in_sizes, int n_in,
                              void* d_out, int out_size, void* d_ws, size_t ws_size,
                              hipStream_t stream)
{
    const float* f_atoms = (const float*)d_in[0];
    const float* f_bonds = (const float*)d_in[1];
    const int*   a2b     = (const int*)d_in[2];
    const int*   b2a     = (const int*)d_in[3];
    const int*   b2revb  = (const int*)d_in[4];
    const float* W_i = (const float*)d_in[5];
    const float* b_i = (const float*)d_in[6];
    const float* W_h = (const float*)d_in[7];
    const float* b_h = (const float*)d_in[8];
    const float* ln_msg_s = (const float*)d_in[9];
    const float* ln_msg_b = (const float*)d_in[10];
    const float* W_o = (const float*)d_in[11];
    const float* b_o = (const float*)d_in[12];
    const float* ln_atom_s = (const float*)d_in[13];
    const float* ln_atom_b = (const float*)d_in[14];
    const float* q_w = (const float*)d_in[15];
    const float* q_b = (const float*)d_in[16];
    const float* k_w = (const float*)d_in[17];
    const float* k_b = (const float*)d_in[18];
    const float* v_w = (const float*)d_in[19];
    const float* v_b = (const float*)d_in[20];
    const float* o_w = (const float*)d_in[21];
    const float* o_b = (const float*)d_in[22];
    const float* ln1_s = (const float*)d_in[23];
    const float* ln1_b = (const float*)d_in[24];
    const float* ln2_s = (const float*)d_in[25];
    const float* ln2_b = (const float*)d_in[26];
    const float* ff1_w = (const float*)d_in[27];
    const float* ff1_b = (const float*)d_in[28];
    const float* ff2_w = (const float*)d_in[29];
    const float* ff2_b = (const float*)d_in[30];
    const float* rquery = (const float*)d_in[31];
    const float* rk_w = (const float*)d_in[32];
    const float* rk_b = (const float*)d_in[33];

    // ---- workspace layout (u16 elements) ----
    const size_t SZ_MSG = (size_t)NB * H;       // 37.75M
    const size_t SZ_NEI = (size_t)NA * H;
    const size_t W_I_SZ  = 256 * KI_PAD;
    const size_t W_H_SZ  = 3 * 256 * 256;
    const size_t W_O_SZ  = 256 * KO_PAD;
    const size_t W_QKV_SZ = 768 * 256;
    const size_t W_OG_SZ = 256 * 256;
    const size_t W_F1_SZ = 512 * 256;
    const size_t W_F2_SZ = 256 * 512;
    const size_t wtotal = W_I_SZ + W_H_SZ + W_O_SZ + W_QKV_SZ + W_OG_SZ + W_F1_SZ + W_F2_SZ;
    const size_t required = (2 * SZ_MSG + SZ_NEI + wtotal) * 2 + 768 * 4 + 257 * 4 + 256;
    if (ws_size < required) {
        diag_k<<<dim3((out_size + 255) / 256), dim3(256), 0, stream>>>(
            (float*)d_out, out_size, (float)(ws_size >> 20));
        return;
    }

    u16* msg    = (u16*)d_ws;
    u16* normed = msg + SZ_MSG;                 // also A_init [NB][192], A_cat [NA][448], qkv, ff1o
    u16* nei    = normed + SZ_MSG;
    u16* wt_i   = nei + SZ_NEI;
    u16* wt_h   = wt_i + W_I_SZ;
    u16* wt_o   = wt_h + W_H_SZ;
    u16* wt_qkv = wt_o + W_O_SZ;
    u16* wt_og  = wt_qkv + W_QKV_SZ;
    u16* wt_f1  = wt_og + W_OG_SZ;
    u16* wt_f2  = wt_f1 + W_F1_SZ;
    float* qkvb = (float*)(wt_f2 + W_F2_SZ);
    float* small = qkvb + 768;

    // aliases
    u16* x    = msg;                            // [NA][256]
    u16* h    = msg + SZ_NEI;                   // [NA][256]
    u16* qkv  = normed;                         // [NA][768]
    u16* ctx  = nei;                            // [NA][256]
    u16* h2   = msg + SZ_NEI;
    u16* ff1o = normed;                         // [NA][512]
    float* out = (float*)d_out;

    dim3 blk(256);
    #define WCVT(W, DST, K, N, KP) wcvt_k<<<dim3(((N)*(KP)+255)/256), blk, 0, stream>>>(W, DST, K, N, KP)

    // ---- prep: weights -> bf16 transposed ----
    WCVT(W_i, wt_i, KINIT, 256, KI_PAD);
    WCVT(W_h,           wt_h,           256, 256, 256);
    WCVT(W_h + 65536,   wt_h + 65536,   256, 256, 256);
    WCVT(W_h + 131072,  wt_h + 131072,  256, 256, 256);
    WCVT(W_o, wt_o, AFEAT + H, 256, KO_PAD);
    WCVT(q_w, wt_qkv,          256, 256, 256);
    WCVT(k_w, wt_qkv + 65536,  256, 256, 256);
    WCVT(v_w, wt_qkv + 131072, 256, 256, 256);
    WCVT(o_w, wt_og, 256, 256, 256);
    WCVT(ff1_w, wt_f1, 256, 512, 256);
    WCVT(ff2_w, wt_f2, 512, 256, 512);
    biaspack_k<<<dim3(1), blk, 0, stream>>>(q_b, k_b, v_b, qkvb);

    // ---- 1. init message GEMM ----
    ainit_k<<<dim3(NB / 4), blk, 0, stream>>>(f_atoms, f_bonds, b2a, normed);
    gemm_mfma_k<true, false><<<dim3(NB / 128, 2), blk, 0, stream>>>(
        normed, KI_PAD, wt_i, b_i, msg, H, KI_PAD);

    // ---- 2. depth loop ----
    for (int t = 0; t < 3; ++t) {
        nei_sum_k<<<dim3(NA / 4), blk, 0, stream>>>(msg, a2b, nei);
        bond_ln_k<<<dim3(NB / 4), blk, 0, stream>>>(nei, msg, b2a, b2revb,
            ln_msg_s + t * H, ln_msg_b + t * H, normed);
        gemm_mfma_k<true, true><<<dim3(NB / 128, 2), blk, 0, stream>>>(
            normed, H, wt_h + (size_t)t * 65536, b_h + t * H, msg, H, H);
    }

    // ---- 3. atom hidden ----
    nei_sum_k<<<dim3(NA / 4), blk, 0, stream>>>(msg, a2b, nei);
    acat_k<<<dim3(NA / 4), blk, 0, stream>>>(f_atoms, nei, normed);
    gemm_mfma_k<true, false><<<dim3(NA / 128, 2), blk, 0, stream>>>(
        normed, KO_PAD, wt_o, b_o, x, H, KO_PAD);
    row_ln_k<<<dim3(NA / 4), blk, 0, stream>>>(x, x, ln_atom_s, ln_atom_b);

    // ---- 4. transformer layer ----
    row_ln_k<<<dim3(NA / 4), blk, 0, stream>>>(x, h, ln1_s, ln1_b);
    gemm_mfma_k<false, false><<<dim3(NA / 128, 6), blk, 0, stream>>>(
        h, H, wt_qkv, qkvb, qkv, 768, H);
    attn_k<<<dim3(NMOL * NHEAD), blk, 0, stream>>>(qkv, ctx);
    gemm_mfma_k<false, true><<<dim3(NA / 128, 2), blk, 0, stream>>>(
        ctx, H, wt_og, o_b, x, H, H);
    row_ln_k<<<dim3(NA / 4), blk, 0, stream>>>(x, h2, ln2_s, ln2_b);
    gemm_mfma_k<true, false><<<dim3(NA / 128, 4), blk, 0, stream>>>(
        h2, H, wt_f1, ff1_b, ff1o, 512, H);
    gemm_mfma_k<false, true><<<dim3(NA / 128, 2), blk, 0, stream>>>(
        ff1o, 512, wt_f2, ff2_b, x, H, 512);

    // ---- 5. readout ----
    readout_prep_k<<<dim3(1), blk, 0, stream>>>(rk_w, rk_b, rquery, small);
    readout_k<<<dim3(NMOL), blk, 0, stream>>>(x, small, out);
}

// Round 4
// 779.794 us; speedup vs baseline: 3.1854x; 1.1867x over previous
//
#include <hip/hip_runtime.h>
#include <hip/hip_bf16.h>
#include <math.h>

#define H 256
#define AFEAT 153
#define BFEAT 14
#define KINIT 167
#define NA 49152
#define NB 147456
#define NMOL 1024
#define APM 48
#define MAXNB 6
#define NHEAD 4
#define HDIM 64
#define EPSLN 1e-5f
#define KI_PAD 192
#define KO_PAD 448

typedef unsigned short u16;
typedef __attribute__((ext_vector_type(8))) short bf16x8;
typedef __attribute__((ext_vector_type(4))) short bf16x4;
typedef __attribute__((ext_vector_type(4))) float f32x4;

__device__ __forceinline__ float gelu_f(float x) {
    return 0.5f * x * (1.0f + erff(x * 0.70710678118654752f));
}
__device__ __forceinline__ float wave_sum(float v) {
    #pragma unroll
    for (int m = 1; m < 64; m <<= 1) v += __shfl_xor(v, m);
    return v;
}
__device__ __forceinline__ float b2f(u16 u) {
    union { unsigned u32; float f; } c; c.u32 = ((unsigned)u) << 16; return c.f;
}
__device__ __forceinline__ u16 f2b(float f) {
    __hip_bfloat16 h = __float2bfloat16(f);
    u16 u; __builtin_memcpy(&u, &h, 2); return u;
}
__device__ __forceinline__ ushort4 f2b4(float a, float b, float c, float d) {
    ushort4 o; o.x = f2b(a); o.y = f2b(b); o.z = f2b(c); o.w = f2b(d); return o;
}

// K=16 bf16 MFMA (4 bf16/lane operands) with name-robust dispatch
__device__ __forceinline__ f32x4 mfma16(bf16x4 a, bf16x4 b, f32x4 c) {
#if __has_builtin(__builtin_amdgcn_mfma_f32_16x16x16bf16_1k)
    return __builtin_amdgcn_mfma_f32_16x16x16bf16_1k(a, b, c, 0, 0, 0);
#elif __has_builtin(__builtin_amdgcn_mfma_f32_16x16x16_bf16_1k)
    return __builtin_amdgcn_mfma_f32_16x16x16_bf16_1k(a, b, c, 0, 0, 0);
#elif __has_builtin(__builtin_amdgcn_mfma_f32_16x16x16_bf16)
    return __builtin_amdgcn_mfma_f32_16x16x16_bf16(a, b, c, 0, 0, 0);
#else
    f32x4 d;
    asm("v_mfma_f32_16x16x16_bf16 %0, %1, %2, %3"
        : "=&v"(d) : "v"(a), "v"(b), "v"(c));
    return d;
#endif
}

// async global->LDS, 16B per lane
typedef const __attribute__((address_space(1))) void* gas_ptr;
typedef __attribute__((address_space(3))) void* las_ptr;
__device__ __forceinline__ void gload_lds16(const u16* g, u16* l) {
    __builtin_amdgcn_global_load_lds((gas_ptr)g, (las_ptr)l, 16, 0, 0);
}

// ================= MFMA GEMM: C[M][Nc] = op(A @ Wt^T + bias) =================
template<bool GELU, bool ACCUM>
__global__ __launch_bounds__(256) void gemm_mfma_k(
    const u16* __restrict__ A, int Ka,
    const u16* __restrict__ Wt,
    const float* __restrict__ bias,
    u16* __restrict__ C, int Nc, int K)
{
    __shared__ __align__(16) u16 As[128 * 64];
    __shared__ __align__(16) u16 Bs[128 * 64];
    const int tid = threadIdx.x;
    const int w = tid >> 6, l = tid & 63;
    const int r0 = blockIdx.x * 128;
    const int cb0 = blockIdx.y * 128;
    const int wr = (w >> 1) * 64;
    const int wc = (w & 1) * 64;

    f32x4 acc[4][4];
    #pragma unroll
    for (int m = 0; m < 4; ++m)
        #pragma unroll
        for (int n = 0; n < 4; ++n) acc[m][n] = (f32x4){0.f, 0.f, 0.f, 0.f};

    const int srow = l >> 3;
    const int sslot = (l & 7) * 16;
    const int ssrc = sslot ^ (srow << 4);

    const int fr = l & 15;
    const int fh = l >> 4;
    const int swz = (fr & 7) << 4;

    for (int k0 = 0; k0 < K; k0 += 64) {
        #pragma unroll
        for (int i = 0; i < 4; ++i) {
            const int seg = w * 4 + i;
            gload_lds16(A + (size_t)(r0 + seg * 8 + srow) * Ka + k0 + (ssrc >> 1),
                        &As[seg * 512]);
            gload_lds16(Wt + (size_t)(cb0 + seg * 8 + srow) * Ka + k0 + (ssrc >> 1),
                        &Bs[seg * 512]);
        }
        __syncthreads();
        #pragma unroll
        for (int s = 0; s < 2; ++s) {
            const int cbyte = ((s * 64 + fh * 16) ^ swz) >> 1;
            bf16x8 af[4], bv[4];
            #pragma unroll
            for (int m = 0; m < 4; ++m)
                af[m] = *(const bf16x8*)&As[(wr + m * 16 + fr) * 64 + cbyte];
            #pragma unroll
            for (int n = 0; n < 4; ++n)
                bv[n] = *(const bf16x8*)&Bs[(wc + n * 16 + fr) * 64 + cbyte];
            #pragma unroll
            for (int m = 0; m < 4; ++m)
                #pragma unroll
                for (int n = 0; n < 4; ++n)
                    acc[m][n] = __builtin_amdgcn_mfma_f32_16x16x32_bf16(
                        af[m], bv[n], acc[m][n], 0, 0, 0);
        }
        __syncthreads();
    }

    float bvv[4];
    #pragma unroll
    for (int n = 0; n < 4; ++n) bvv[n] = bias[cb0 + wc + n * 16 + fr];
    #pragma unroll
    for (int m = 0; m < 4; ++m) {
        #pragma unroll
        for (int n = 0; n < 4; ++n) {
            const int col = cb0 + wc + n * 16 + fr;
            #pragma unroll
            for (int j = 0; j < 4; ++j) {
                const int row = r0 + wr + m * 16 + fh * 4 + j;
                float v = acc[m][n][j] + bvv[n];
                if (GELU) v = gelu_f(v);
                u16* p = &C[(size_t)row * Nc + col];
                if (ACCUM) v += b2f(*p);
                *p = f2b(v);
            }
        }
    }
}

// ============ weight convert+transpose: W f32[K][N] -> Wt bf16[N][Kpad] ============
__global__ __launch_bounds__(256) void wcvt_k(const float* __restrict__ W,
    u16* __restrict__ Wt, int K, int N, int Kpad)
{
    int idx = blockIdx.x * 256 + threadIdx.x;
    if (idx >= N * Kpad) return;
    int n = idx / Kpad, kp = idx - n * Kpad;
    Wt[idx] = (kp < K) ? f2b(W[(size_t)kp * N + n]) : (u16)0;
}

__global__ void biaspack_k(const float* q, const float* k, const float* v, float* dst) {
    int t = threadIdx.x;
    dst[t] = q[t]; dst[256 + t] = k[t]; dst[512 + t] = v[t];
}

// ============ A_init bf16 [NB][192] ============
__global__ __launch_bounds__(256) void ainit_k(const float* __restrict__ fa,
    const float* __restrict__ fb, const int* __restrict__ b2a, u16* __restrict__ dst)
{
    const int w = threadIdx.x >> 6, l = threadIdx.x & 63;
    const int row = blockIdx.x * 4 + w;
    const int a = b2a[row];
    const float* fsrc = fa + (size_t)a * AFEAT;
    u16* d = dst + (size_t)row * KI_PAD;
    #pragma unroll
    for (int i = 0; i < 3; ++i) {
        int c = l + i * 64;
        float v;
        if (c < AFEAT) v = fsrc[c];
        else if (c < KINIT) v = fb[(size_t)row * BFEAT + (c - AFEAT)];
        else v = 0.f;
        d[c] = f2b(v);
    }
}

// ============ A_cat bf16 [NA][448] ============
__global__ __launch_bounds__(256) void acat_k(const float* __restrict__ fa,
    const u16* __restrict__ nei, u16* __restrict__ dst)
{
    const int w = threadIdx.x >> 6, l = threadIdx.x & 63;
    const int row = blockIdx.x * 4 + w;
    const float* fsrc = fa + (size_t)row * AFEAT;
    const u16* nsrc = nei + (size_t)row * H;
    u16* d = dst + (size_t)row * KO_PAD;
    #pragma unroll
    for (int i = 0; i < 7; ++i) {
        int c = l + i * 64;
        u16 v;
        if (c < AFEAT) v = f2b(fsrc[c]);
        else if (c < AFEAT + H) v = nsrc[c - AFEAT];
        else v = 0;
        d[c] = v;
    }
}

// ---------------- gather-sum ----------------
__global__ __launch_bounds__(256) void nei_sum_k(const u16* __restrict__ msg,
    const int* __restrict__ a2b, u16* __restrict__ nei)
{
    const int wave = threadIdx.x >> 6;
    const int lane = threadIdx.x & 63;
    const int atom = blockIdx.x * 4 + wave;
    float ax = 0.f, ay = 0.f, az = 0.f, aw = 0.f;
    #pragma unroll
    for (int j = 0; j < MAXNB; ++j) {
        int b = a2b[atom * MAXNB + j];
        ushort4 v = *(const ushort4*)(msg + (size_t)b * H + lane * 4);
        ax += b2f(v.x); ay += b2f(v.y); az += b2f(v.z); aw += b2f(v.w);
    }
    *(ushort4*)(nei + (size_t)atom * H + lane * 4) = f2b4(ax, ay, az, aw);
}

// ---------------- per-bond LN ----------------
__global__ __launch_bounds__(256) void bond_ln_k(const u16* __restrict__ nei,
    const u16* __restrict__ msg, const int* __restrict__ b2a,
    const int* __restrict__ b2revb, const float* __restrict__ s,
    const float* __restrict__ b, u16* __restrict__ out)
{
    const int wave = threadIdx.x >> 6;
    const int lane = threadIdx.x & 63;
    const int bond = blockIdx.x * 4 + wave;
    const int a = b2a[bond];
    const int rb = b2revb[bond];
    ushort4 un = *(const ushort4*)(nei + (size_t)a * H + lane * 4);
    ushort4 um = *(const ushort4*)(msg + (size_t)rb * H + lane * 4);
    float vx = b2f(un.x) - b2f(um.x), vy = b2f(un.y) - b2f(um.y);
    float vz = b2f(un.z) - b2f(um.z), vw = b2f(un.w) - b2f(um.w);
    float mean = wave_sum(vx + vy + vz + vw) * (1.0f / H);
    float dx = vx - mean, dy = vy - mean, dz = vz - mean, dw = vw - mean;
    float var = wave_sum(dx * dx + dy * dy + dz * dz + dw * dw) * (1.0f / H);
    float inv = rsqrtf(var + EPSLN);
    float4 s4 = *(const float4*)(s + lane * 4);
    float4 b4 = *(const float4*)(b + lane * 4);
    *(ushort4*)(out + (size_t)bond * H + lane * 4) =
        f2b4(dx * inv * s4.x + b4.x, dy * inv * s4.y + b4.y,
             dz * inv * s4.z + b4.z, dw * inv * s4.w + b4.w);
}

// ---------------- per-row LN ----------------
__global__ __launch_bounds__(256) void row_ln_k(const u16* __restrict__ in,
    u16* __restrict__ out, const float* __restrict__ s, const float* __restrict__ b)
{
    const int wave = threadIdx.x >> 6;
    const int lane = threadIdx.x & 63;
    const int row = blockIdx.x * 4 + wave;
    ushort4 u = *(const ushort4*)(in + (size_t)row * H + lane * 4);
    float vx = b2f(u.x), vy = b2f(u.y), vz = b2f(u.z), vw = b2f(u.w);
    float mean = wave_sum(vx + vy + vz + vw) * (1.0f / H);
    float dx = vx - mean, dy = vy - mean, dz = vz - mean, dw = vw - mean;
    float var = wave_sum(dx * dx + dy * dy + dz * dz + dw * dw) * (1.0f / H);
    float inv = rsqrtf(var + EPSLN);
    float4 s4 = *(const float4*)(s + lane * 4);
    float4 b4 = *(const float4*)(b + lane * 4);
    *(ushort4*)(out + (size_t)row * H + lane * 4) =
        f2b4(dx * inv * s4.x + b4.x, dy * inv * s4.y + b4.y,
             dz * inv * s4.z + b4.z, dw * inv * s4.w + b4.w);
}

// ============== MFMA attention: 1 block/mol, 1 wave/head ==============
// S^T = K@Q^T (16x16x32), in-reg softmax over k, ctx^T = V^T@P^T (16x16x16).
#define VPAD 268
__global__ __launch_bounds__(256) void attn_mfma_k(const u16* __restrict__ qkv,
    u16* __restrict__ ctx)
{
    __shared__ u16 Vs[48][VPAD];
    const int mol = blockIdx.x;
    const int tid = threadIdx.x;
    const int w = tid >> 6;          // head
    const int l = tid & 63;
    const int fr = l & 15;
    const int fh = l >> 4;
    const size_t qb = (size_t)mol * APM * 768;

    // stage V (all heads): 48 rows x 256 u16, coalesced; 8B LDS writes (pad 268)
    {
        const int r = tid >> 4;
        const int c = (tid & 15) * 16;
        #pragma unroll
        for (int i = 0; i < 3; ++i) {
            const int row = r + i * 16;
            const u16* src = qkv + qb + (size_t)row * 768 + 512 + c;
            ushort4 a0 = *(const ushort4*)(src);
            ushort4 a1 = *(const ushort4*)(src + 4);
            ushort4 a2 = *(const ushort4*)(src + 8);
            ushort4 a3 = *(const ushort4*)(src + 12);
            *(ushort4*)&Vs[row][c]      = a0;
            *(ushort4*)&Vs[row][c + 4]  = a1;
            *(ushort4*)&Vs[row][c + 8]  = a2;
            *(ushort4*)&Vs[row][c + 12] = a3;
        }
    }
    __syncthreads();

    // ---- S^T = K @ Q^T  (rows = key atom, cols = query atom) ----
    f32x4 st[3][3];
    {
        bf16x8 kf[3][2], qf[3][2];
        #pragma unroll
        for (int t = 0; t < 3; ++t)
            #pragma unroll
            for (int ks = 0; ks < 2; ++ks) {
                const size_t rowb = qb + (size_t)(t * 16 + fr) * 768;
                kf[t][ks] = *(const bf16x8*)(qkv + rowb + 256 + w * 64 + ks * 32 + fh * 8);
                qf[t][ks] = *(const bf16x8*)(qkv + rowb +       w * 64 + ks * 32 + fh * 8);
            }
        #pragma unroll
        for (int mi = 0; mi < 3; ++mi)
            #pragma unroll
            for (int ni = 0; ni < 3; ++ni) {
                f32x4 a = (f32x4){0.f, 0.f, 0.f, 0.f};
                a = __builtin_amdgcn_mfma_f32_16x16x32_bf16(kf[mi][0], qf[ni][0], a, 0, 0, 0);
                a = __builtin_amdgcn_mfma_f32_16x16x32_bf16(kf[mi][1], qf[ni][1], a, 0, 0, 0);
                st[mi][ni] = a;
            }
    }

    // ---- softmax over k (rows of S^T); division deferred ----
    float inv_sum[3];
    #pragma unroll
    for (int ni = 0; ni < 3; ++ni) {
        float m = -1e30f;
        #pragma unroll
        for (int mi = 0; mi < 3; ++mi)
            #pragma unroll
            for (int j = 0; j < 4; ++j) m = fmaxf(m, st[mi][ni][j]);
        m = fmaxf(m, __shfl_xor(m, 16));
        m = fmaxf(m, __shfl_xor(m, 32));
        float s = 0.f;
        #pragma unroll
        for (int mi = 0; mi < 3; ++mi)
            #pragma unroll
            for (int j = 0; j < 4; ++j) {
                float e = expf((st[mi][ni][j] - m) * 0.125f);
                st[mi][ni][j] = e;
                s += e;
            }
        s += __shfl_xor(s, 16);
        s += __shfl_xor(s, 32);
        inv_sum[ni] = 1.0f / s;
    }

    // ---- P^T bf16 fragments (k-mapping (lane>>4)*4+e matches 16x16x16 B-frag) ----
    bf16x4 pf[3][3];
    #pragma unroll
    for (int mi = 0; mi < 3; ++mi)
        #pragma unroll
        for (int ni = 0; ni < 3; ++ni) {
            bf16x4 p;
            p[0] = (short)f2b(st[mi][ni][0]);
            p[1] = (short)f2b(st[mi][ni][1]);
            p[2] = (short)f2b(st[mi][ni][2]);
            p[3] = (short)f2b(st[mi][ni][3]);
            pf[mi][ni] = p;
        }

    // ---- ctx^T = V^T @ P^T ----
    f32x4 co[4][3];
    #pragma unroll
    for (int dt = 0; dt < 4; ++dt)
        #pragma unroll
        for (int ni = 0; ni < 3; ++ni) co[dt][ni] = (f32x4){0.f, 0.f, 0.f, 0.f};
    #pragma unroll
    for (int kt = 0; kt < 3; ++kt) {
        bf16x4 vf[4];
        #pragma unroll
        for (int dt = 0; dt < 4; ++dt) {
            const int colu = w * 64 + dt * 16 + fr;
            bf16x4 t;
            #pragma unroll
            for (int e = 0; e < 4; ++e)
                t[e] = (short)Vs[kt * 16 + fh * 4 + e][colu];
            vf[dt] = t;
        }
        #pragma unroll
        for (int dt = 0; dt < 4; ++dt)
            #pragma unroll
            for (int ni = 0; ni < 3; ++ni)
                co[dt][ni] = mfma16(vf[dt], pf[kt][ni], co[dt][ni]);
    }

    // ---- write ctx[atom][head*64+d] (4 consecutive d per lane-reg) ----
    #pragma unroll
    for (int ni = 0; ni < 3; ++ni) {
        const float is = inv_sum[ni];
        u16* rowp = ctx + (size_t)(mol * APM + ni * 16 + fr) * H + w * 64;
        #pragma unroll
        for (int dt = 0; dt < 4; ++dt) {
            *(ushort4*)(rowp + dt * 16 + fh * 4) =
                f2b4(co[dt][ni][0] * is, co[dt][ni][1] * is,
                     co[dt][ni][2] * is, co[dt][ni][3] * is);
        }
    }
}

// ---------------- readout prep ----------------
__global__ __launch_bounds__(256) void readout_prep_k(const float* __restrict__ rk_w,
    const float* __restrict__ rk_b, const float* __restrict__ query, float* __restrict__ small)
{
    __shared__ float qsh[256];
    __shared__ float red[4];
    const int t = threadIdx.x;
    qsh[t] = query[t];
    __syncthreads();
    float acc = 0.f;
    #pragma unroll
    for (int c = 0; c < 256; c += 4) {
        float4 w = *(const float4*)&rk_w[(size_t)t * 256 + c];
        acc += w.x * qsh[c] + w.y * qsh[c+1] + w.z * qsh[c+2] + w.w * qsh[c+3];
    }
    small[t] = acc;
    float term = wave_sum(rk_b[t] * qsh[t]);
    if ((t & 63) == 0) red[t >> 6] = term;
    __syncthreads();
    if (t == 0) small[256] = red[0] + red[1] + red[2] + red[3];
}

// ---------------- readout ----------------
__global__ __launch_bounds__(256) void readout_k(const u16* __restrict__ x,
    const float* __restrict__ small, float* __restrict__ out)
{
    __shared__ float sc[48];
    __shared__ float rvs[256];
    const int mol = blockIdx.x;
    const int t = threadIdx.x;
    const int wave = t >> 6, lane = t & 63;
    rvs[t] = small[t];
    __syncthreads();
    const float c0 = small[256];
    const size_t xb = (size_t)mol * APM * H;
    for (int i = 0; i < 12; ++i) {
        int s = wave * 12 + i;
        ushort4 xu = *(const ushort4*)(x + xb + (size_t)s * H + lane * 4);
        float dot = b2f(xu.x) * rvs[lane*4] + b2f(xu.y) * rvs[lane*4+1]
                  + b2f(xu.z) * rvs[lane*4+2] + b2f(xu.w) * rvs[lane*4+3];
        dot = wave_sum(dot);
        if (lane == 0) sc[s] = dot + c0;
    }
    __syncthreads();
    if (wave == 0) {
        float v = (lane < 48) ? sc[lane] : -1e30f;
        float mx = v;
        #pragma unroll
        for (int m = 1; m < 64; m <<= 1) mx = fmaxf(mx, __shfl_xor(mx, m));
        float e = (lane < 48) ? expf(v - mx) : 0.f;
        float sum = wave_sum(e);
        if (lane < 48) sc[lane] = e / sum;
    }
    __syncthreads();
    float acc = 0.f;
    for (int s = 0; s < 48; ++s) acc += sc[s] * b2f(x[xb + (size_t)s * H + t]);
    out[(size_t)mol * H + t] = acc;
}

__global__ void diag_k(float* out, int n, float val) {
    int i = blockIdx.x * 256 + threadIdx.x;
    if (i < n) out[i] = (i == 0) ? val : 0.f;
}

extern "C" void kernel_launch(void* const* d_in, const int* in_sizes, int n_in,
                              void* d_out, int out_size, void* d_ws, size_t ws_size,
                              hipStream_t stream)
{
    const float* f_atoms = (const float*)d_in[0];
    const float* f_bonds = (const float*)d_in[1];
    const int*   a2b     = (const int*)d_in[2];
    const int*   b2a     = (const int*)d_in[3];
    const int*   b2revb  = (const int*)d_in[4];
    const float* W_i = (const float*)d_in[5];
    const float* b_i = (const float*)d_in[6];
    const float* W_h = (const float*)d_in[7];
    const float* b_h = (const float*)d_in[8];
    const float* ln_msg_s = (const float*)d_in[9];
    const float* ln_msg_b = (const float*)d_in[10];
    const float* W_o = (const float*)d_in[11];
    const float* b_o = (const float*)d_in[12];
    const float* ln_atom_s = (const float*)d_in[13];
    const float* ln_atom_b = (const float*)d_in[14];
    const float* q_w = (const float*)d_in[15];
    const float* q_b = (const float*)d_in[16];
    const float* k_w = (const float*)d_in[17];
    const float* k_b = (const float*)d_in[18];
    const float* v_w = (const float*)d_in[19];
    const float* v_b = (const float*)d_in[20];
    const float* o_w = (const float*)d_in[21];
    const float* o_b = (const float*)d_in[22];
    const float* ln1_s = (const float*)d_in[23];
    const float* ln1_b = (const float*)d_in[24];
    const float* ln2_s = (const float*)d_in[25];
    const float* ln2_b = (const float*)d_in[26];
    const float* ff1_w = (const float*)d_in[27];
    const float* ff1_b = (const float*)d_in[28];
    const float* ff2_w = (const float*)d_in[29];
    const float* ff2_b = (const float*)d_in[30];
    const float* rquery = (const float*)d_in[31];
    const float* rk_w = (const float*)d_in[32];
    const float* rk_b = (const float*)d_in[33];

    const size_t SZ_MSG = (size_t)NB * H;
    const size_t SZ_NEI = (size_t)NA * H;
    const size_t W_I_SZ  = 256 * KI_PAD;
    const size_t W_H_SZ  = 3 * 256 * 256;
    const size_t W_O_SZ  = 256 * KO_PAD;
    const size_t W_QKV_SZ = 768 * 256;
    const size_t W_OG_SZ = 256 * 256;
    const size_t W_F1_SZ = 512 * 256;
    const size_t W_F2_SZ = 256 * 512;
    const size_t wtotal = W_I_SZ + W_H_SZ + W_O_SZ + W_QKV_SZ + W_OG_SZ + W_F1_SZ + W_F2_SZ;
    const size_t required = (2 * SZ_MSG + SZ_NEI + wtotal) * 2 + 768 * 4 + 257 * 4 + 256;
    if (ws_size < required) {
        diag_k<<<dim3((out_size + 255) / 256), dim3(256), 0, stream>>>(
            (float*)d_out, out_size, (float)(ws_size >> 20));
        return;
    }

    u16* msg    = (u16*)d_ws;
    u16* normed = msg + SZ_MSG;
    u16* nei    = normed + SZ_MSG;
    u16* wt_i   = nei + SZ_NEI;
    u16* wt_h   = wt_i + W_I_SZ;
    u16* wt_o   = wt_h + W_H_SZ;
    u16* wt_qkv = wt_o + W_O_SZ;
    u16* wt_og  = wt_qkv + W_QKV_SZ;
    u16* wt_f1  = wt_og + W_OG_SZ;
    u16* wt_f2  = wt_f1 + W_F1_SZ;
    float* qkvb = (float*)(wt_f2 + W_F2_SZ);
    float* small = qkvb + 768;

    u16* x    = msg;
    u16* h    = msg + SZ_NEI;
    u16* qkv  = normed;
    u16* ctx  = nei;
    u16* h2   = msg + SZ_NEI;
    u16* ff1o = normed;
    float* out = (float*)d_out;

    dim3 blk(256);
    #define WCVT(W, DST, K, N, KP) wcvt_k<<<dim3(((N)*(KP)+255)/256), blk, 0, stream>>>(W, DST, K, N, KP)

    WCVT(W_i, wt_i, KINIT, 256, KI_PAD);
    WCVT(W_h,           wt_h,           256, 256, 256);
    WCVT(W_h + 65536,   wt_h + 65536,   256, 256, 256);
    WCVT(W_h + 131072,  wt_h + 131072,  256, 256, 256);
    WCVT(W_o, wt_o, AFEAT + H, 256, KO_PAD);
    WCVT(q_w, wt_qkv,          256, 256, 256);
    WCVT(k_w, wt_qkv + 65536,  256, 256, 256);
    WCVT(v_w, wt_qkv + 131072, 256, 256, 256);
    WCVT(o_w, wt_og, 256, 256, 256);
    WCVT(ff1_w, wt_f1, 256, 512, 256);
    WCVT(ff2_w, wt_f2, 512, 256, 512);
    biaspack_k<<<dim3(1), blk, 0, stream>>>(q_b, k_b, v_b, qkvb);

    // ---- 1. init message GEMM ----
    ainit_k<<<dim3(NB / 4), blk, 0, stream>>>(f_atoms, f_bonds, b2a, normed);
    gemm_mfma_k<true, false><<<dim3(NB / 128, 2), blk, 0, stream>>>(
        normed, KI_PAD, wt_i, b_i, msg, H, KI_PAD);

    // ---- 2. depth loop ----
    for (int t = 0; t < 3; ++t) {
        nei_sum_k<<<dim3(NA / 4), blk, 0, stream>>>(msg, a2b, nei);
        bond_ln_k<<<dim3(NB / 4), blk, 0, stream>>>(nei, msg, b2a, b2revb,
            ln_msg_s + t * H, ln_msg_b + t * H, normed);
        gemm_mfma_k<true, true><<<dim3(NB / 128, 2), blk, 0, stream>>>(
            normed, H, wt_h + (size_t)t * 65536, b_h + t * H, msg, H, H);
    }

    // ---- 3. atom hidden ----
    nei_sum_k<<<dim3(NA / 4), blk, 0, stream>>>(msg, a2b, nei);
    acat_k<<<dim3(NA / 4), blk, 0, stream>>>(f_atoms, nei, normed);
    gemm_mfma_k<true, false><<<dim3(NA / 128, 2), blk, 0, stream>>>(
        normed, KO_PAD, wt_o, b_o, x, H, KO_PAD);
    row_ln_k<<<dim3(NA / 4), blk, 0, stream>>>(x, x, ln_atom_s, ln_atom_b);

    // ---- 4. transformer layer ----
    row_ln_k<<<dim3(NA / 4), blk, 0, stream>>>(x, h, ln1_s, ln1_b);
    gemm_mfma_k<false, false><<<dim3(NA / 128, 6), blk, 0, stream>>>(
        h, H, wt_qkv, qkvb, qkv, 768, H);
    attn_mfma_k<<<dim3(NMOL), blk, 0, stream>>>(qkv, ctx);
    gemm_mfma_k<false, true><<<dim3(NA / 128, 2), blk, 0, stream>>>(
        ctx, H, wt_og, o_b, x, H, H);
    row_ln_k<<<dim3(NA / 4), blk, 0, stream>>>(x, h2, ln2_s, ln2_b);
    gemm_mfma_k<true, false><<<dim3(NA / 128, 4), blk, 0, stream>>>(
        h2, H, wt_f1, ff1_b, ff1o, 512, H);
    gemm_mfma_k<false, true><<<dim3(NA / 128, 2), blk, 0, stream>>>(
        ff1o, 512, wt_f2, ff2_b, x, H, 512);

    // ---- 5. readout ----
    readout_prep_k<<<dim3(1), blk, 0, stream>>>(rk_w, rk_b, rquery, small);
    readout_k<<<dim3(NMOL), blk, 0, stream>>>(x, small, out);
}

// Round 5
// 735.999 us; speedup vs baseline: 3.3750x; 1.0595x over previous
//
#include <hip/hip_runtime.h>
#include <hip/hip_bf16.h>
#include <math.h>

#define H 256
#define AFEAT 153
#define BFEAT 14
#define KINIT 167
#define NA 49152
#define NB 147456
#define NMOL 1024
#define APM 48
#define MAXNB 6
#define NHEAD 4
#define HDIM 64
#define EPSLN 1e-5f
#define KI_PAD 192
#define KO_PAD 448

typedef unsigned short u16;
typedef __attribute__((ext_vector_type(8))) short bf16x8;
typedef __attribute__((ext_vector_type(4))) short bf16x4;
typedef __attribute__((ext_vector_type(4))) float f32x4;

__device__ __forceinline__ float gelu_f(float x) {
    return 0.5f * x * (1.0f + erff(x * 0.70710678118654752f));
}
__device__ __forceinline__ float wave_sum(float v) {
    #pragma unroll
    for (int m = 1; m < 64; m <<= 1) v += __shfl_xor(v, m);
    return v;
}
__device__ __forceinline__ float b2f(u16 u) {
    union { unsigned u32; float f; } c; c.u32 = ((unsigned)u) << 16; return c.f;
}
__device__ __forceinline__ u16 f2b(float f) {
    __hip_bfloat16 h = __float2bfloat16(f);
    u16 u; __builtin_memcpy(&u, &h, 2); return u;
}
__device__ __forceinline__ ushort4 f2b4(float a, float b, float c, float d) {
    ushort4 o; o.x = f2b(a); o.y = f2b(b); o.z = f2b(c); o.w = f2b(d); return o;
}
// bf16-pair add on a packed u32 (for vectorized ACCUM epilogues)
__device__ __forceinline__ unsigned addbf2(unsigned a, unsigned b) {
    float lo = b2f((u16)(a & 0xffff)) + b2f((u16)(b & 0xffff));
    float hi = b2f((u16)(a >> 16)) + b2f((u16)(b >> 16));
    return ((unsigned)f2b(hi) << 16) | (unsigned)f2b(lo);
}
__device__ __forceinline__ uint4 addbf8(uint4 a, uint4 b) {
    uint4 r;
    r.x = addbf2(a.x, b.x); r.y = addbf2(a.y, b.y);
    r.z = addbf2(a.z, b.z); r.w = addbf2(a.w, b.w);
    return r;
}

// K=16 bf16 MFMA with name-robust dispatch (used by attention)
__device__ __forceinline__ f32x4 mfma16(bf16x4 a, bf16x4 b, f32x4 c) {
#if __has_builtin(__builtin_amdgcn_mfma_f32_16x16x16bf16_1k)
    return __builtin_amdgcn_mfma_f32_16x16x16bf16_1k(a, b, c, 0, 0, 0);
#elif __has_builtin(__builtin_amdgcn_mfma_f32_16x16x16_bf16_1k)
    return __builtin_amdgcn_mfma_f32_16x16x16_bf16_1k(a, b, c, 0, 0, 0);
#elif __has_builtin(__builtin_amdgcn_mfma_f32_16x16x16_bf16)
    return __builtin_amdgcn_mfma_f32_16x16x16_bf16(a, b, c, 0, 0, 0);
#else
    f32x4 d;
    asm("v_mfma_f32_16x16x16_bf16 %0, %1, %2, %3"
        : "=&v"(d) : "v"(a), "v"(b), "v"(c));
    return d;
#endif
}

// async global->LDS, 16B per lane
typedef const __attribute__((address_space(1))) void* gas_ptr;
typedef __attribute__((address_space(3))) void* las_ptr;
__device__ __forceinline__ void gload_lds16(const u16* g, u16* l) {
    __builtin_amdgcn_global_load_lds((gas_ptr)g, (las_ptr)l, 16, 0, 0);
}

// ================= MFMA GEMM (generic K): C[M][Nc] = op(A @ Wt^T + bias) =================
// block 256 thr / 4 waves, tile 128x128, BK=64, vectorized LDS-transpose epilogue.
template<bool GELU, bool ACCUM>
__global__ __launch_bounds__(256) void gemm_mfma_k(
    const u16* __restrict__ A, int Ka,
    const u16* __restrict__ Wt,
    const float* __restrict__ bias,
    u16* __restrict__ C, int Nc, int K)
{
    __shared__ __align__(16) u16 S[128 * 128];      // 32 KB: As | Bs, reused by epilogue
    u16* As = S;                // 128 rows x 64 u16
    u16* Bs = S + 8192;         // 128 rows x 64 u16
    const int tid = threadIdx.x;
    const int w = tid >> 6, l = tid & 63;
    const int r0 = blockIdx.x * 128;
    const int cb0 = blockIdx.y * 128;
    const int wr = (w >> 1) * 64;
    const int wc = (w & 1) * 64;

    f32x4 acc[4][4];
    #pragma unroll
    for (int m = 0; m < 4; ++m)
        #pragma unroll
        for (int n = 0; n < 4; ++n) acc[m][n] = (f32x4){0.f, 0.f, 0.f, 0.f};

    const int srow = l >> 3;
    const int ssrc = ((l & 7) * 16) ^ (srow << 4);
    const int fr = l & 15;
    const int fh = l >> 4;
    const int swz = (fr & 7) << 4;

    for (int k0 = 0; k0 < K; k0 += 64) {
        #pragma unroll
        for (int i = 0; i < 4; ++i) {
            const int seg = w * 4 + i;
            gload_lds16(A + (size_t)(r0 + seg * 8 + srow) * Ka + k0 + (ssrc >> 1),
                        &As[seg * 512]);
            gload_lds16(Wt + (size_t)(cb0 + seg * 8 + srow) * Ka + k0 + (ssrc >> 1),
                        &Bs[seg * 512]);
        }
        __syncthreads();
        #pragma unroll
        for (int s = 0; s < 2; ++s) {
            const int cbyte = ((s * 64 + fh * 16) ^ swz) >> 1;
            bf16x8 af[4], bv[4];
            #pragma unroll
            for (int m = 0; m < 4; ++m)
                af[m] = *(const bf16x8*)&As[(wr + m * 16 + fr) * 64 + cbyte];
            #pragma unroll
            for (int n = 0; n < 4; ++n)
                bv[n] = *(const bf16x8*)&Bs[(wc + n * 16 + fr) * 64 + cbyte];
            #pragma unroll
            for (int m = 0; m < 4; ++m)
                #pragma unroll
                for (int n = 0; n < 4; ++n)
                    acc[m][n] = __builtin_amdgcn_mfma_f32_16x16x32_bf16(
                        af[m], bv[n], acc[m][n], 0, 0, 0);
        }
        __syncthreads();
    }

    // ---- epilogue: bf16 tile -> LDS (swizzled), vectorized coalesced store ----
    float bvv[4];
    #pragma unroll
    for (int n = 0; n < 4; ++n) bvv[n] = bias[cb0 + wc + n * 16 + fr];
    #pragma unroll
    for (int m = 0; m < 4; ++m)
        #pragma unroll
        for (int n = 0; n < 4; ++n) {
            const int col = wc + n * 16 + fr;
            #pragma unroll
            for (int j = 0; j < 4; ++j) {
                const int row = wr + m * 16 + fh * 4 + j;
                float v = acc[m][n][j] + bvv[n];
                if (GELU) v = gelu_f(v);
                *(u16*)((char*)S + row * 256 + ((col * 2) ^ ((row & 7) << 4))) = f2b(v);
            }
        }
    __syncthreads();
    {
        const int rrow = tid >> 1;           // 0..127
        const int rch = (tid & 1) * 128;     // byte offset of 64-u16 half
        const int rswz = (rrow & 7) << 4;
        u16* gp = C + (size_t)(r0 + rrow) * Nc + cb0 + (tid & 1) * 64;
        #pragma unroll
        for (int q = 0; q < 8; ++q) {
            uint4 dv = *(const uint4*)((const char*)S + rrow * 256 + ((rch + q * 16) ^ rswz));
            if (ACCUM) {
                uint4 ov = *(const uint4*)(gp + q * 8);
                dv = addbf8(dv, ov);
            }
            *(uint4*)(gp + q * 8) = dv;
        }
    }
}

// ===== fused LayerNorm + GEMM, K=256 fixed, tile 64 rows x 256 cols, 512 thr =====
// A row produced in-kernel: LN(ld.load4(row)) * lns + lnb, staged bf16 to LDS.
struct LGather {            // depth loop: nei[b2a[row]] - msg[b2revb[row]]
    const u16* nei; const u16* msg; const int* b2a; const int* b2revb;
    __device__ __forceinline__ float4 load4(int row, int lane) const {
        const int a = b2a[row], rv = b2revb[row];
        ushort4 un = *(const ushort4*)(nei + (size_t)a * H + lane * 4);
        ushort4 um = *(const ushort4*)(msg + (size_t)rv * H + lane * 4);
        return make_float4(b2f(un.x) - b2f(um.x), b2f(un.y) - b2f(um.y),
                           b2f(un.z) - b2f(um.z), b2f(un.w) - b2f(um.w));
    }
};
struct LPlain {             // transformer: plain row of X
    const u16* X;
    __device__ __forceinline__ float4 load4(int row, int lane) const {
        ushort4 u = *(const ushort4*)(X + (size_t)row * H + lane * 4);
        return make_float4(b2f(u.x), b2f(u.y), b2f(u.z), b2f(u.w));
    }
};

template<class L, bool GELU, bool ACCUM>
__global__ __launch_bounds__(512, 4) void fln_gemm_k(
    L ld, const u16* __restrict__ Wt,          // [Ntot][256]
    const float* __restrict__ lns, const float* __restrict__ lnb,
    const float* __restrict__ bias,            // [Ntot]
    const u16* __restrict__ Cold,              // ACCUM source
    u16* __restrict__ C, int Nc)
{
    __shared__ __align__(16) u16 SH[64 * 256 + 256 * 64];   // A 32KB | B 32KB
    u16* Alds = SH;             // 64 rows x 256 u16 (512 B rows), swizzled
    u16* Blds = SH + 64 * 256;  // 256 rows x 64 u16 (BK=64), swizzled
    const int tid = threadIdx.x;
    const int w = tid >> 6, l = tid & 63;
    const int r0 = blockIdx.x * 64;
    const int cb0 = blockIdx.y * 256;
    const int fr = l & 15, fh = l >> 4;
    const int swzf = (fr & 7) << 4;

    // ---- stage A with fused LayerNorm: 8 rows per wave ----
    {
        float4 sv = *(const float4*)(lns + l * 4);
        float4 bv = *(const float4*)(lnb + l * 4);
        #pragma unroll
        for (int i = 0; i < 8; ++i) {
            const int r = w * 8 + i;
            float4 v = ld.load4(r0 + r, l);
            float mean = wave_sum(v.x + v.y + v.z + v.w) * (1.0f / H);
            float dx = v.x - mean, dy = v.y - mean, dz = v.z - mean, dw = v.w - mean;
            float var = wave_sum(dx * dx + dy * dy + dz * dz + dw * dw) * (1.0f / H);
            float inv = rsqrtf(var + EPSLN);
            ushort4 o = f2b4(dx * inv * sv.x + bv.x, dy * inv * sv.y + bv.y,
                             dz * inv * sv.z + bv.z, dw * inv * sv.w + bv.w);
            *(ushort4*)((char*)&Alds[(size_t)r * 256] + ((l * 8) ^ ((r & 7) << 4))) = o;
        }
    }

    f32x4 acc[2][4];
    #pragma unroll
    for (int m = 0; m < 2; ++m)
        #pragma unroll
        for (int n = 0; n < 4; ++n) acc[m][n] = (f32x4){0.f, 0.f, 0.f, 0.f};

    const int wr = (w >> 2) * 32;       // wave row offset (2 groups)
    const int wc = (w & 3) * 64;        // wave col offset (4 groups)

    for (int kk = 0; kk < 4; ++kk) {
        // stage B K-step: 256 rows x 64 u16; seg covers 8 rows (1 KB)
        #pragma unroll
        for (int i = 0; i < 4; ++i) {
            const int seg = w * 4 + i;
            const int n = seg * 8 + (l >> 3);
            const int sb = ((l & 7) * 16) ^ ((n & 7) << 4);
            gload_lds16(Wt + (size_t)(cb0 + n) * H + kk * 64 + (sb >> 1),
                        &Blds[seg * 512]);
        }
        __syncthreads();
        #pragma unroll
        for (int s = 0; s < 2; ++s) {
            bf16x8 af[2], bv[4];
            #pragma unroll
            for (int m = 0; m < 2; ++m)
                af[m] = *(const bf16x8*)((const char*)&Alds[(size_t)(wr + m * 16 + fr) * 256]
                        + ((kk * 128 + s * 64 + fh * 16) ^ swzf));
            #pragma unroll
            for (int n = 0; n < 4; ++n)
                bv[n] = *(const bf16x8*)((const char*)&Blds[(size_t)(wc + n * 16 + fr) * 64]
                        + ((s * 64 + fh * 16) ^ swzf));
            #pragma unroll
            for (int m = 0; m < 2; ++m)
                #pragma unroll
                for (int n = 0; n < 4; ++n)
                    acc[m][n] = __builtin_amdgcn_mfma_f32_16x16x32_bf16(
                        af[m], bv[n], acc[m][n], 0, 0, 0);
        }
        __syncthreads();
    }

    // ---- epilogue: tile -> Alds (reuse, 64x256 u16), vectorized store ----
    float bvv[4];
    #pragma unroll
    for (int n = 0; n < 4; ++n) bvv[n] = bias[cb0 + wc + n * 16 + fr];
    #pragma unroll
    for (int m = 0; m < 2; ++m)
        #pragma unroll
        for (int n = 0; n < 4; ++n) {
            const int col = wc + n * 16 + fr;
            #pragma unroll
            for (int j = 0; j < 4; ++j) {
                const int row = wr + m * 16 + fh * 4 + j;
                float v = acc[m][n][j] + bvv[n];
                if (GELU) v = gelu_f(v);
                *(u16*)((char*)&Alds[(size_t)row * 256] + ((col * 2) ^ ((row & 7) << 4))) = f2b(v);
            }
        }
    __syncthreads();
    {
        const int rrow = tid >> 3;          // 0..63
        const int rch = (tid & 7) * 64;     // byte offset of 32-u16 chunk
        const int rswz = (rrow & 7) << 4;
        u16* gp = C + (size_t)(r0 + rrow) * Nc + cb0 + (tid & 7) * 32;
        const u16* op = Cold + (size_t)(r0 + rrow) * Nc + cb0 + (tid & 7) * 32;
        #pragma unroll
        for (int q = 0; q < 4; ++q) {
            uint4 dv = *(const uint4*)((const char*)&Alds[(size_t)rrow * 256]
                        + ((rch + q * 16) ^ rswz));
            if (ACCUM) {
                uint4 ov = *(const uint4*)(op + q * 8);
                dv = addbf8(dv, ov);
            }
            *(uint4*)(gp + q * 8) = dv;
        }
    }
}

// ============ weight convert+transpose: W f32[K][N] -> Wt bf16[N][Kpad] ============
__global__ __launch_bounds__(256) void wcvt_k(const float* __restrict__ W,
    u16* __restrict__ Wt, int K, int N, int Kpad)
{
    int idx = blockIdx.x * 256 + threadIdx.x;
    if (idx >= N * Kpad) return;
    int n = idx / Kpad, kp = idx - n * Kpad;
    Wt[idx] = (kp < K) ? f2b(W[(size_t)kp * N + n]) : (u16)0;
}

__global__ void biaspack_k(const float* q, const float* k, const float* v, float* dst) {
    int t = threadIdx.x;
    dst[t] = q[t]; dst[256 + t] = k[t]; dst[512 + t] = v[t];
}

// ============ A_init bf16 [NB][192] ============
__global__ __launch_bounds__(256) void ainit_k(const float* __restrict__ fa,
    const float* __restrict__ fb, const int* __restrict__ b2a, u16* __restrict__ dst)
{
    const int w = threadIdx.x >> 6, l = threadIdx.x & 63;
    const int row = blockIdx.x * 4 + w;
    const int a = b2a[row];
    const float* fsrc = fa + (size_t)a * AFEAT;
    u16* d = dst + (size_t)row * KI_PAD;
    #pragma unroll
    for (int i = 0; i < 3; ++i) {
        int c = l + i * 64;
        float v;
        if (c < AFEAT) v = fsrc[c];
        else if (c < KINIT) v = fb[(size_t)row * BFEAT + (c - AFEAT)];
        else v = 0.f;
        d[c] = f2b(v);
    }
}

// ============ A_cat bf16 [NA][448] ============
__global__ __launch_bounds__(256) void acat_k(const float* __restrict__ fa,
    const u16* __restrict__ nei, u16* __restrict__ dst)
{
    const int w = threadIdx.x >> 6, l = threadIdx.x & 63;
    const int row = blockIdx.x * 4 + w;
    const float* fsrc = fa + (size_t)row * AFEAT;
    const u16* nsrc = nei + (size_t)row * H;
    u16* d = dst + (size_t)row * KO_PAD;
    #pragma unroll
    for (int i = 0; i < 7; ++i) {
        int c = l + i * 64;
        u16 v;
        if (c < AFEAT) v = f2b(fsrc[c]);
        else if (c < AFEAT + H) v = nsrc[c - AFEAT];
        else v = 0;
        d[c] = v;
    }
}

// ---------------- gather-sum ----------------
__global__ __launch_bounds__(256) void nei_sum_k(const u16* __restrict__ msg,
    const int* __restrict__ a2b, u16* __restrict__ nei)
{
    const int wave = threadIdx.x >> 6;
    const int lane = threadIdx.x & 63;
    const int atom = blockIdx.x * 4 + wave;
    float ax = 0.f, ay = 0.f, az = 0.f, aw = 0.f;
    #pragma unroll
    for (int j = 0; j < MAXNB; ++j) {
        int b = a2b[atom * MAXNB + j];
        ushort4 v = *(const ushort4*)(msg + (size_t)b * H + lane * 4);
        ax += b2f(v.x); ay += b2f(v.y); az += b2f(v.z); aw += b2f(v.w);
    }
    *(ushort4*)(nei + (size_t)atom * H + lane * 4) = f2b4(ax, ay, az, aw);
}

// ---------------- per-row LN (ln_atom only) ----------------
__global__ __launch_bounds__(256) void row_ln_k(const u16* __restrict__ in,
    u16* __restrict__ out, const float* __restrict__ s, const float* __restrict__ b)
{
    const int wave = threadIdx.x >> 6;
    const int lane = threadIdx.x & 63;
    const int row = blockIdx.x * 4 + wave;
    ushort4 u = *(const ushort4*)(in + (size_t)row * H + lane * 4);
    float vx = b2f(u.x), vy = b2f(u.y), vz = b2f(u.z), vw = b2f(u.w);
    float mean = wave_sum(vx + vy + vz + vw) * (1.0f / H);
    float dx = vx - mean, dy = vy - mean, dz = vz - mean, dw = vw - mean;
    float var = wave_sum(dx * dx + dy * dy + dz * dz + dw * dw) * (1.0f / H);
    float inv = rsqrtf(var + EPSLN);
    float4 s4 = *(const float4*)(s + lane * 4);
    float4 b4 = *(const float4*)(b + lane * 4);
    *(ushort4*)(out + (size_t)row * H + lane * 4) =
        f2b4(dx * inv * s4.x + b4.x, dy * inv * s4.y + b4.y,
             dz * inv * s4.z + b4.z, dw * inv * s4.w + b4.w);
}

// ============== MFMA attention: 1 block/mol, 1 wave/head ==============
#define VPAD 268
__global__ __launch_bounds__(256) void attn_mfma_k(const u16* __restrict__ qkv,
    u16* __restrict__ ctx)
{
    __shared__ u16 Vs[48][VPAD];
    const int mol = blockIdx.x;
    const int tid = threadIdx.x;
    const int w = tid >> 6;
    const int l = tid & 63;
    const int fr = l & 15;
    const int fh = l >> 4;
    const size_t qb = (size_t)mol * APM * 768;

    {
        const int r = tid >> 4;
        const int c = (tid & 15) * 16;
        #pragma unroll
        for (int i = 0; i < 3; ++i) {
            const int row = r + i * 16;
            const u16* src = qkv + qb + (size_t)row * 768 + 512 + c;
            ushort4 a0 = *(const ushort4*)(src);
            ushort4 a1 = *(const ushort4*)(src + 4);
            ushort4 a2 = *(const ushort4*)(src + 8);
            ushort4 a3 = *(const ushort4*)(src + 12);
            *(ushort4*)&Vs[row][c]      = a0;
            *(ushort4*)&Vs[row][c + 4]  = a1;
            *(ushort4*)&Vs[row][c + 8]  = a2;
            *(ushort4*)&Vs[row][c + 12] = a3;
        }
    }
    __syncthreads();

    f32x4 st[3][3];
    {
        bf16x8 kf[3][2], qf[3][2];
        #pragma unroll
        for (int t = 0; t < 3; ++t)
            #pragma unroll
            for (int ks = 0; ks < 2; ++ks) {
                const size_t rowb = qb + (size_t)(t * 16 + fr) * 768;
                kf[t][ks] = *(const bf16x8*)(qkv + rowb + 256 + w * 64 + ks * 32 + fh * 8);
                qf[t][ks] = *(const bf16x8*)(qkv + rowb +       w * 64 + ks * 32 + fh * 8);
            }
        #pragma unroll
        for (int mi = 0; mi < 3; ++mi)
            #pragma unroll
            for (int ni = 0; ni < 3; ++ni) {
                f32x4 a = (f32x4){0.f, 0.f, 0.f, 0.f};
                a = __builtin_amdgcn_mfma_f32_16x16x32_bf16(kf[mi][0], qf[ni][0], a, 0, 0, 0);
                a = __builtin_amdgcn_mfma_f32_16x16x32_bf16(kf[mi][1], qf[ni][1], a, 0, 0, 0);
                st[mi][ni] = a;
            }
    }

    float inv_sum[3];
    #pragma unroll
    for (int ni = 0; ni < 3; ++ni) {
        float m = -1e30f;
        #pragma unroll
        for (int mi = 0; mi < 3; ++mi)
            #pragma unroll
            for (int j = 0; j < 4; ++j) m = fmaxf(m, st[mi][ni][j]);
        m = fmaxf(m, __shfl_xor(m, 16));
        m = fmaxf(m, __shfl_xor(m, 32));
        float s = 0.f;
        #pragma unroll
        for (int mi = 0; mi < 3; ++mi)
            #pragma unroll
            for (int j = 0; j < 4; ++j) {
                float e = expf((st[mi][ni][j] - m) * 0.125f);
                st[mi][ni][j] = e;
                s += e;
            }
        s += __shfl_xor(s, 16);
        s += __shfl_xor(s, 32);
        inv_sum[ni] = 1.0f / s;
    }

    bf16x4 pf[3][3];
    #pragma unroll
    for (int mi = 0; mi < 3; ++mi)
        #pragma unroll
        for (int ni = 0; ni < 3; ++ni) {
            bf16x4 p;
            p[0] = (short)f2b(st[mi][ni][0]);
            p[1] = (short)f2b(st[mi][ni][1]);
            p[2] = (short)f2b(st[mi][ni][2]);
            p[3] = (short)f2b(st[mi][ni][3]);
            pf[mi][ni] = p;
        }

    f32x4 co[4][3];
    #pragma unroll
    for (int dt = 0; dt < 4; ++dt)
        #pragma unroll
        for (int ni = 0; ni < 3; ++ni) co[dt][ni] = (f32x4){0.f, 0.f, 0.f, 0.f};
    #pragma unroll
    for (int kt = 0; kt < 3; ++kt) {
        bf16x4 vf[4];
        #pragma unroll
        for (int dt = 0; dt < 4; ++dt) {
            const int colu = w * 64 + dt * 16 + fr;
            bf16x4 t;
            #pragma unroll
            for (int e = 0; e < 4; ++e)
                t[e] = (short)Vs[kt * 16 + fh * 4 + e][colu];
            vf[dt] = t;
        }
        #pragma unroll
        for (int dt = 0; dt < 4; ++dt)
            #pragma unroll
            for (int ni = 0; ni < 3; ++ni)
                co[dt][ni] = mfma16(vf[dt], pf[kt][ni], co[dt][ni]);
    }

    #pragma unroll
    for (int ni = 0; ni < 3; ++ni) {
        const float is = inv_sum[ni];
        u16* rowp = ctx + (size_t)(mol * APM + ni * 16 + fr) * H + w * 64;
        #pragma unroll
        for (int dt = 0; dt < 4; ++dt) {
            *(ushort4*)(rowp + dt * 16 + fh * 4) =
                f2b4(co[dt][ni][0] * is, co[dt][ni][1] * is,
                     co[dt][ni][2] * is, co[dt][ni][3] * is);
        }
    }
}

// ---------------- readout prep ----------------
__global__ __launch_bounds__(256) void readout_prep_k(const float* __restrict__ rk_w,
    const float* __restrict__ rk_b, const float* __restrict__ query, float* __restrict__ small)
{
    __shared__ float qsh[256];
    __shared__ float red[4];
    const int t = threadIdx.x;
    qsh[t] = query[t];
    __syncthreads();
    float acc = 0.f;
    #pragma unroll
    for (int c = 0; c < 256; c += 4) {
        float4 w = *(const float4*)&rk_w[(size_t)t * 256 + c];
        acc += w.x * qsh[c] + w.y * qsh[c+1] + w.z * qsh[c+2] + w.w * qsh[c+3];
    }
    small[t] = acc;
    float term = wave_sum(rk_b[t] * qsh[t]);
    if ((t & 63) == 0) red[t >> 6] = term;
    __syncthreads();
    if (t == 0) small[256] = red[0] + red[1] + red[2] + red[3];
}

// ---------------- readout ----------------
__global__ __launch_bounds__(256) void readout_k(const u16* __restrict__ x,
    const float* __restrict__ small, float* __restrict__ out)
{
    __shared__ float sc[48];
    __shared__ float rvs[256];
    const int mol = blockIdx.x;
    const int t = threadIdx.x;
    const int wave = t >> 6, lane = t & 63;
    rvs[t] = small[t];
    __syncthreads();
    const float c0 = small[256];
    const size_t xb = (size_t)mol * APM * H;
    for (int i = 0; i < 12; ++i) {
        int s = wave * 12 + i;
        ushort4 xu = *(const ushort4*)(x + xb + (size_t)s * H + lane * 4);
        float dot = b2f(xu.x) * rvs[lane*4] + b2f(xu.y) * rvs[lane*4+1]
                  + b2f(xu.z) * rvs[lane*4+2] + b2f(xu.w) * rvs[lane*4+3];
        dot = wave_sum(dot);
        if (lane == 0) sc[s] = dot + c0;
    }
    __syncthreads();
    if (wave == 0) {
        float v = (lane < 48) ? sc[lane] : -1e30f;
        float mx = v;
        #pragma unroll
        for (int m = 1; m < 64; m <<= 1) mx = fmaxf(mx, __shfl_xor(mx, m));
        float e = (lane < 48) ? expf(v - mx) : 0.f;
        float sum = wave_sum(e);
        if (lane < 48) sc[lane] = e / sum;
    }
    __syncthreads();
    float acc = 0.f;
    for (int s = 0; s < 48; ++s) acc += sc[s] * b2f(x[xb + (size_t)s * H + t]);
    out[(size_t)mol * H + t] = acc;
}

__global__ void diag_k(float* out, int n, float val) {
    int i = blockIdx.x * 256 + threadIdx.x;
    if (i < n) out[i] = (i == 0) ? val : 0.f;
}

extern "C" void kernel_launch(void* const* d_in, const int* in_sizes, int n_in,
                              void* d_out, int out_size, void* d_ws, size_t ws_size,
                              hipStream_t stream)
{
    const float* f_atoms = (const float*)d_in[0];
    const float* f_bonds = (const float*)d_in[1];
    const int*   a2b     = (const int*)d_in[2];
    const int*   b2a     = (const int*)d_in[3];
    const int*   b2revb  = (const int*)d_in[4];
    const float* W_i = (const float*)d_in[5];
    const float* b_i = (const float*)d_in[6];
    const float* W_h = (const float*)d_in[7];
    const float* b_h = (const float*)d_in[8];
    const float* ln_msg_s = (const float*)d_in[9];
    const float* ln_msg_b = (const float*)d_in[10];
    const float* W_o = (const float*)d_in[11];
    const float* b_o = (const float*)d_in[12];
    const float* ln_atom_s = (const float*)d_in[13];
    const float* ln_atom_b = (const float*)d_in[14];
    const float* q_w = (const float*)d_in[15];
    const float* q_b = (const float*)d_in[16];
    const float* k_w = (const float*)d_in[17];
    const float* k_b = (const float*)d_in[18];
    const float* v_w = (const float*)d_in[19];
    const float* v_b = (const float*)d_in[20];
    const float* o_w = (const float*)d_in[21];
    const float* o_b = (const float*)d_in[22];
    const float* ln1_s = (const float*)d_in[23];
    const float* ln1_b = (const float*)d_in[24];
    const float* ln2_s = (const float*)d_in[25];
    const float* ln2_b = (const float*)d_in[26];
    const float* ff1_w = (const float*)d_in[27];
    const float* ff1_b = (const float*)d_in[28];
    const float* ff2_w = (const float*)d_in[29];
    const float* ff2_b = (const float*)d_in[30];
    const float* rquery = (const float*)d_in[31];
    const float* rk_w = (const float*)d_in[32];
    const float* rk_b = (const float*)d_in[33];

    const size_t SZ_MSG = (size_t)NB * H;
    const size_t SZ_NEI = (size_t)NA * H;
    const size_t W_I_SZ  = 256 * KI_PAD;
    const size_t W_H_SZ  = 3 * 256 * 256;
    const size_t W_O_SZ  = 256 * KO_PAD;
    const size_t W_QKV_SZ = 768 * 256;
    const size_t W_OG_SZ = 256 * 256;
    const size_t W_F1_SZ = 512 * 256;
    const size_t W_F2_SZ = 256 * 512;
    const size_t wtotal = W_I_SZ + W_H_SZ + W_O_SZ + W_QKV_SZ + W_OG_SZ + W_F1_SZ + W_F2_SZ;
    const size_t required = (2 * SZ_MSG + SZ_NEI + wtotal) * 2 + 768 * 4 + 257 * 4 + 256;
    if (ws_size < required) {
        diag_k<<<dim3((out_size + 255) / 256), dim3(256), 0, stream>>>(
            (float*)d_out, out_size, (float)(ws_size >> 20));
        return;
    }

    u16* msgA   = (u16*)d_ws;                    // ping
    u16* msgB   = msgA + SZ_MSG;                 // pong / staging
    u16* nei    = msgB + SZ_MSG;
    u16* wt_i   = nei + SZ_NEI;
    u16* wt_h   = wt_i + W_I_SZ;
    u16* wt_o   = wt_h + W_H_SZ;
    u16* wt_qkv = wt_o + W_O_SZ;
    u16* wt_og  = wt_qkv + W_QKV_SZ;
    u16* wt_f1  = wt_og + W_OG_SZ;
    u16* wt_f2  = wt_f1 + W_F1_SZ;
    float* qkvb = (float*)(wt_f2 + W_F2_SZ);
    float* small = qkvb + 768;
    float* out = (float*)d_out;

    dim3 blk(256);
    dim3 blk5(512);
    #define WCVT(W, DST, K, N, KP) wcvt_k<<<dim3(((N)*(KP)+255)/256), blk, 0, stream>>>(W, DST, K, N, KP)

    WCVT(W_i, wt_i, KINIT, 256, KI_PAD);
    WCVT(W_h,           wt_h,           256, 256, 256);
    WCVT(W_h + 65536,   wt_h + 65536,   256, 256, 256);
    WCVT(W_h + 131072,  wt_h + 131072,  256, 256, 256);
    WCVT(W_o, wt_o, AFEAT + H, 256, KO_PAD);
    WCVT(q_w, wt_qkv,          256, 256, 256);
    WCVT(k_w, wt_qkv + 65536,  256, 256, 256);
    WCVT(v_w, wt_qkv + 131072, 256, 256, 256);
    WCVT(o_w, wt_og, 256, 256, 256);
    WCVT(ff1_w, wt_f1, 256, 512, 256);
    WCVT(ff2_w, wt_f2, 512, 256, 512);
    biaspack_k<<<dim3(1), blk, 0, stream>>>(q_b, k_b, v_b, qkvb);

    // ---- 1. init message GEMM (A_init staged in msgB) ----
    ainit_k<<<dim3(NB / 4), blk, 0, stream>>>(f_atoms, f_bonds, b2a, msgB);
    gemm_mfma_k<true, false><<<dim3(NB / 128, 2), blk, 0, stream>>>(
        msgB, KI_PAD, wt_i, b_i, msgA, H, KI_PAD);

    // ---- 2. depth loop: fused gather+LN+GEMM, ping-pong msg ----
    u16* cur = msgA;
    u16* oth = msgB;
    for (int t = 0; t < 3; ++t) {
        nei_sum_k<<<dim3(NA / 4), blk, 0, stream>>>(cur, a2b, nei);
        fln_gemm_k<LGather, true, true><<<dim3(NB / 64, 1), blk5, 0, stream>>>(
            LGather{nei, cur, b2a, b2revb}, wt_h + (size_t)t * 65536,
            ln_msg_s + t * H, ln_msg_b + t * H, b_h + t * H,
            cur, oth, H);
        u16* tmp = cur; cur = oth; oth = tmp;
    }
    // cur = final message (msgB); oth = msgA free

    // ---- 3. atom hidden ----
    nei_sum_k<<<dim3(NA / 4), blk, 0, stream>>>(cur, a2b, nei);
    acat_k<<<dim3(NA / 4), blk, 0, stream>>>(f_atoms, nei, oth);   // A_cat in msgA
    u16* x = cur;                                                  // [NA][256] in msgB
    gemm_mfma_k<true, false><<<dim3(NA / 128, 2), blk, 0, stream>>>(
        oth, KO_PAD, wt_o, b_o, x, H, KO_PAD);
    row_ln_k<<<dim3(NA / 4), blk, 0, stream>>>(x, x, ln_atom_s, ln_atom_b);

    // ---- 4. transformer layer ----
    u16* qkv = oth;                                                // [NA][768] in msgA
    fln_gemm_k<LPlain, false, false><<<dim3(NA / 64, 3), blk5, 0, stream>>>(
        LPlain{x}, wt_qkv, ln1_s, ln1_b, qkvb, x, qkv, 768);
    u16* ctx = nei;
    attn_mfma_k<<<dim3(NMOL), blk, 0, stream>>>(qkv, ctx);
    gemm_mfma_k<false, true><<<dim3(NA / 128, 2), blk, 0, stream>>>(
        ctx, H, wt_og, o_b, x, H, H);
    u16* ff1o = oth;                                               // [NA][512] in msgA
    fln_gemm_k<LPlain, true, false><<<dim3(NA / 64, 2), blk5, 0, stream>>>(
        LPlain{x}, wt_f1, ln2_s, ln2_b, ff1_b, x, ff1o, 512);
    gemm_mfma_k<false, true><<<dim3(NA / 128, 2), blk, 0, stream>>>(
        ff1o, 512, wt_f2, ff2_b, x, H, 512);

    // ---- 5. readout ----
    readout_prep_k<<<dim3(1), blk, 0, stream>>>(rk_w, rk_b, rquery, small);
    readout_k<<<dim3(NMOL), blk, 0, stream>>>(x, small, out);
}

// Round 6
// 734.505 us; speedup vs baseline: 3.3818x; 1.0020x over previous
//
#include <hip/hip_runtime.h>
#include <hip/hip_bf16.h>
#include <math.h>

#define H 256
#define AFEAT 153
#define BFEAT 14
#define KINIT 167
#define NA 49152
#define NB 147456
#define NMOL 1024
#define APM 48
#define MAXNB 6
#define NHEAD 4
#define HDIM 64
#define EPSLN 1e-5f
#define KI_PAD 192
#define KO_PAD 448

typedef unsigned short u16;
typedef __attribute__((ext_vector_type(8))) short bf16x8;
typedef __attribute__((ext_vector_type(4))) short bf16x4;
typedef __attribute__((ext_vector_type(4))) float f32x4;

// fast GELU: x * sigmoid(1.5957691x(1+0.044715x^2)); |err vs erf-gelu| < 4e-4
__device__ __forceinline__ float gelu_f(float x) {
    float t = -1.5957691216f * x * (1.0f + 0.044715f * x * x);
    float e = __expf(t);
#if __has_builtin(__builtin_amdgcn_rcpf)
    return x * __builtin_amdgcn_rcpf(1.0f + e);
#else
    return x / (1.0f + e);
#endif
}
__device__ __forceinline__ float wave_sum(float v) {
    #pragma unroll
    for (int m = 1; m < 64; m <<= 1) v += __shfl_xor(v, m);
    return v;
}
__device__ __forceinline__ float b2f(u16 u) {
    union { unsigned u32; float f; } c; c.u32 = ((unsigned)u) << 16; return c.f;
}
__device__ __forceinline__ float blo(unsigned w) {
    union { unsigned u; float f; } c; c.u = w << 16; return c.f;
}
__device__ __forceinline__ float bhi(unsigned w) {
    union { unsigned u; float f; } c; c.u = w & 0xffff0000u; return c.f;
}
__device__ __forceinline__ u16 f2b(float f) {
    __hip_bfloat16 h = __float2bfloat16(f);
    u16 u; __builtin_memcpy(&u, &h, 2); return u;
}
__device__ __forceinline__ ushort4 f2b4(float a, float b, float c, float d) {
    ushort4 o; o.x = f2b(a); o.y = f2b(b); o.z = f2b(c); o.w = f2b(d); return o;
}
__device__ __forceinline__ void up8(uint4 u, float* v) {
    v[0]=blo(u.x); v[1]=bhi(u.x); v[2]=blo(u.y); v[3]=bhi(u.y);
    v[4]=blo(u.z); v[5]=bhi(u.z); v[6]=blo(u.w); v[7]=bhi(u.w);
}
__device__ __forceinline__ unsigned addbf2(unsigned a, unsigned b) {
    float lo = b2f((u16)(a & 0xffff)) + b2f((u16)(b & 0xffff));
    float hi = b2f((u16)(a >> 16)) + b2f((u16)(b >> 16));
    return ((unsigned)f2b(hi) << 16) | (unsigned)f2b(lo);
}
__device__ __forceinline__ uint4 addbf8(uint4 a, uint4 b) {
    uint4 r;
    r.x = addbf2(a.x, b.x); r.y = addbf2(a.y, b.y);
    r.z = addbf2(a.z, b.z); r.w = addbf2(a.w, b.w);
    return r;
}

__device__ __forceinline__ f32x4 mfma16(bf16x4 a, bf16x4 b, f32x4 c) {
#if __has_builtin(__builtin_amdgcn_mfma_f32_16x16x16bf16_1k)
    return __builtin_amdgcn_mfma_f32_16x16x16bf16_1k(a, b, c, 0, 0, 0);
#elif __has_builtin(__builtin_amdgcn_mfma_f32_16x16x16_bf16_1k)
    return __builtin_amdgcn_mfma_f32_16x16x16_bf16_1k(a, b, c, 0, 0, 0);
#elif __has_builtin(__builtin_amdgcn_mfma_f32_16x16x16_bf16)
    return __builtin_amdgcn_mfma_f32_16x16x16_bf16(a, b, c, 0, 0, 0);
#else
    f32x4 d;
    asm("v_mfma_f32_16x16x16_bf16 %0, %1, %2, %3"
        : "=&v"(d) : "v"(a), "v"(b), "v"(c));
    return d;
#endif
}

typedef const __attribute__((address_space(1))) void* gas_ptr;
typedef __attribute__((address_space(3))) void* las_ptr;
__device__ __forceinline__ void gload_lds16(const u16* g, u16* l) {
    __builtin_amdgcn_global_load_lds((gas_ptr)g, (las_ptr)l, 16, 0, 0);
}

// ================= MFMA GEMM (generic K): C[M][Nc] = op(A @ Wt^T + bias) =================
template<bool GELU, bool ACCUM>
__global__ __launch_bounds__(256) void gemm_mfma_k(
    const u16* __restrict__ A, int Ka,
    const u16* __restrict__ Wt,
    const float* __restrict__ bias,
    u16* __restrict__ C, int Nc, int K)
{
    __shared__ __align__(16) u16 S[128 * 128];
    u16* As = S;
    u16* Bs = S + 8192;
    const int tid = threadIdx.x;
    const int w = tid >> 6, l = tid & 63;
    const int r0 = blockIdx.x * 128;
    const int cb0 = blockIdx.y * 128;
    const int wr = (w >> 1) * 64;
    const int wc = (w & 1) * 64;

    f32x4 acc[4][4];
    #pragma unroll
    for (int m = 0; m < 4; ++m)
        #pragma unroll
        for (int n = 0; n < 4; ++n) acc[m][n] = (f32x4){0.f, 0.f, 0.f, 0.f};

    const int srow = l >> 3;
    const int ssrc = ((l & 7) * 16) ^ (srow << 4);
    const int fr = l & 15;
    const int fh = l >> 4;
    const int swz = (fr & 7) << 4;

    for (int k0 = 0; k0 < K; k0 += 64) {
        #pragma unroll
        for (int i = 0; i < 4; ++i) {
            const int seg = w * 4 + i;
            gload_lds16(A + (size_t)(r0 + seg * 8 + srow) * Ka + k0 + (ssrc >> 1),
                        &As[seg * 512]);
            gload_lds16(Wt + (size_t)(cb0 + seg * 8 + srow) * Ka + k0 + (ssrc >> 1),
                        &Bs[seg * 512]);
        }
        __syncthreads();
        #pragma unroll
        for (int s = 0; s < 2; ++s) {
            const int cbyte = ((s * 64 + fh * 16) ^ swz) >> 1;
            bf16x8 af[4], bv[4];
            #pragma unroll
            for (int m = 0; m < 4; ++m)
                af[m] = *(const bf16x8*)&As[(wr + m * 16 + fr) * 64 + cbyte];
            #pragma unroll
            for (int n = 0; n < 4; ++n)
                bv[n] = *(const bf16x8*)&Bs[(wc + n * 16 + fr) * 64 + cbyte];
            #pragma unroll
            for (int m = 0; m < 4; ++m)
                #pragma unroll
                for (int n = 0; n < 4; ++n)
                    acc[m][n] = __builtin_amdgcn_mfma_f32_16x16x32_bf16(
                        af[m], bv[n], acc[m][n], 0, 0, 0);
        }
        __syncthreads();
    }

    float bvv[4];
    #pragma unroll
    for (int n = 0; n < 4; ++n) bvv[n] = bias[cb0 + wc + n * 16 + fr];
    #pragma unroll
    for (int m = 0; m < 4; ++m)
        #pragma unroll
        for (int n = 0; n < 4; ++n) {
            const int col = wc + n * 16 + fr;
            #pragma unroll
            for (int j = 0; j < 4; ++j) {
                const int row = wr + m * 16 + fh * 4 + j;
                float v = acc[m][n][j] + bvv[n];
                if (GELU) v = gelu_f(v);
                *(u16*)((char*)S + row * 256 + ((col * 2) ^ ((row & 7) << 4))) = f2b(v);
            }
        }
    __syncthreads();
    {
        const int rrow = tid >> 1;
        const int rch = (tid & 1) * 128;
        const int rswz = (rrow & 7) << 4;
        u16* gp = C + (size_t)(r0 + rrow) * Nc + cb0 + (tid & 1) * 64;
        #pragma unroll
        for (int q = 0; q < 8; ++q) {
            uint4 dv = *(const uint4*)((const char*)S + rrow * 256 + ((rch + q * 16) ^ rswz));
            if (ACCUM) {
                uint4 ov = *(const uint4*)(gp + q * 8);
                dv = addbf8(dv, ov);
            }
            *(uint4*)(gp + q * 8) = dv;
        }
    }
}

// ===== fused LN + GEMM, K=256, tile 64x256, 512 thr, BK=32 double-buffered B =====
struct LGather {            // depth loop: nei[b2a[row]] - msg[b2revb[row]]
    const u16* nei; const u16* msg; const int* b2a; const int* b2revb;
    __device__ __forceinline__ void load16(int row, int g, float* v) const {
        const int a = b2a[row], rv = b2revb[row];
        const uint4* np = (const uint4*)(nei + (size_t)a * H + g * 16);
        const uint4* mp = (const uint4*)(msg + (size_t)rv * H + g * 16);
        float nv[16], mv[16];
        up8(np[0], nv); up8(np[1], nv + 8);
        up8(mp[0], mv); up8(mp[1], mv + 8);
        #pragma unroll
        for (int j = 0; j < 16; ++j) v[j] = nv[j] - mv[j];
    }
};
struct LPlain {
    const u16* X;
    __device__ __forceinline__ void load16(int row, int g, float* v) const {
        const uint4* p = (const uint4*)(X + (size_t)row * H + g * 16);
        up8(p[0], v); up8(p[1], v + 8);
    }
};

template<class L, bool GELU, bool ACCUM>
__global__ __launch_bounds__(512, 4) void fln_gemm_k(
    L ld, const u16* __restrict__ Wt,          // [Ntot][256]
    const float* __restrict__ lns, const float* __restrict__ lnb,
    const float* __restrict__ bias,
    const u16* __restrict__ Cold,
    u16* __restrict__ C, int Nc)
{
    __shared__ __align__(16) u16 SH[64 * 256 + 2 * 256 * 32];   // A 32KB | B0 16KB | B1 16KB
    u16* Alds = SH;
    u16* Bbuf0 = SH + 16384;
    u16* Bbuf1 = SH + 16384 + 8192;
    const int tid = threadIdx.x;
    const int w = tid >> 6, l = tid & 63;
    const int r0 = blockIdx.x * 64;
    const int cb0 = blockIdx.y * 256;
    const int fr = l & 15, fh = l >> 4;
    const int swzf = (fr & 7) << 4;

    // T14: prefetch ACCUM source early (consumed in epilogue)
    uint4 oldv[4];
    if (ACCUM) {
        const u16* op = Cold + (size_t)(r0 + (tid >> 3)) * Nc + cb0 + (tid & 7) * 32;
        #pragma unroll
        for (int q = 0; q < 4; ++q) oldv[q] = *(const uint4*)(op + q * 8);
    }

    // stage B for kk=0 first — latency hides under the LN stage
    #define STAGE_B(BB, KK) do {                                               \
        _Pragma("unroll")                                                      \
        for (int j_ = 0; j_ < 2; ++j_) {                                       \
            const int seg_ = w * 2 + j_;                                       \
            const int n_ = seg_ * 16 + (l >> 2);                               \
            const int u_ = (n_ & 3) ^ ((n_ >> 2) & 3);                         \
            gload_lds16(Wt + (size_t)(cb0 + n_) * H + (KK) * 32                \
                        + (((l & 3) ^ u_) << 3), (BB) + seg_ * 512);           \
        }                                                                      \
    } while (0)
    STAGE_B(Bbuf0, 0);

    // ---- A stage: 16-lane-group LayerNorm, 2 passes x 4 rows per wave ----
    {
        const int g = l & 15;
        float4 sv[4], bb[4];
        #pragma unroll
        for (int q = 0; q < 4; ++q) {
            sv[q] = *(const float4*)(lns + g * 16 + q * 4);
            bb[q] = *(const float4*)(lnb + g * 16 + q * 4);
        }
        #pragma unroll
        for (int i = 0; i < 2; ++i) {
            const int r = w * 8 + i * 4 + (l >> 4);
            float v[16];
            ld.load16(r0 + r, g, v);
            float s = 0.f, s2 = 0.f;
            #pragma unroll
            for (int j = 0; j < 16; ++j) { s += v[j]; s2 = fmaf(v[j], v[j], s2); }
            #pragma unroll
            for (int m = 1; m < 16; m <<= 1) {
                s += __shfl_xor(s, m);
                s2 += __shfl_xor(s2, m);
            }
            const float mean = s * (1.0f / H);
            const float var = fmaxf(s2 * (1.0f / H) - mean * mean, 0.f);
            const float inv = rsqrtf(var + EPSLN);
            const int swr = (r & 7) << 4;
            #pragma unroll
            for (int q = 0; q < 4; ++q) {
                const float* sq = (const float*)&sv[q];
                const float* bq = (const float*)&bb[q];
                ushort4 o = f2b4((v[q*4+0]-mean)*inv*sq[0] + bq[0],
                                 (v[q*4+1]-mean)*inv*sq[1] + bq[1],
                                 (v[q*4+2]-mean)*inv*sq[2] + bq[2],
                                 (v[q*4+3]-mean)*inv*sq[3] + bq[3]);
                *(ushort4*)((char*)Alds + r * 512 + ((g * 32 + q * 8) ^ swr)) = o;
            }
        }
    }

    f32x4 acc[2][4];
    #pragma unroll
    for (int m = 0; m < 2; ++m)
        #pragma unroll
        for (int n = 0; n < 4; ++n) acc[m][n] = (f32x4){0.f, 0.f, 0.f, 0.f};

    const int wr = (w >> 2) * 32;
    const int wc = (w & 3) * 64;

    __syncthreads();   // drains B0 gloads + A ds_writes

    #pragma unroll
    for (int kk = 0; kk < 8; ++kk) {
        if (kk < 7) STAGE_B((kk & 1) ? Bbuf0 : Bbuf1, kk + 1);   // next buffer
        const u16* Bb = (kk & 1) ? Bbuf1 : Bbuf0;
        bf16x8 af[2], bv[4];
        #pragma unroll
        for (int m = 0; m < 2; ++m)
            af[m] = *(const bf16x8*)((const char*)Alds + (wr + m * 16 + fr) * 512
                    + ((kk * 64 + fh * 16) ^ swzf));
        #pragma unroll
        for (int n = 0; n < 4; ++n) {
            const int nc = wc + n * 16 + fr;
            const int u = (nc & 3) ^ ((nc >> 2) & 3);
            bv[n] = *(const bf16x8*)((const char*)Bb + nc * 64 + ((fh ^ u) << 4));
        }
        #pragma unroll
        for (int m = 0; m < 2; ++m)
            #pragma unroll
            for (int n = 0; n < 4; ++n)
                acc[m][n] = __builtin_amdgcn_mfma_f32_16x16x32_bf16(
                    af[m], bv[n], acc[m][n], 0, 0, 0);
        __syncthreads();   // drains next-buf gloads; guards buffer swap
    }
    #undef STAGE_B

    // ---- epilogue: tile -> Alds, vectorized coalesced store ----
    float bvv[4];
    #pragma unroll
    for (int n = 0; n < 4; ++n) bvv[n] = bias[cb0 + wc + n * 16 + fr];
    #pragma unroll
    for (int m = 0; m < 2; ++m)
        #pragma unroll
        for (int n = 0; n < 4; ++n) {
            const int col = wc + n * 16 + fr;
            #pragma unroll
            for (int j = 0; j < 4; ++j) {
                const int row = wr + m * 16 + fh * 4 + j;
                float v = acc[m][n][j] + bvv[n];
                if (GELU) v = gelu_f(v);
                *(u16*)((char*)Alds + row * 512 + ((col * 2) ^ ((row & 7) << 4))) = f2b(v);
            }
        }
    __syncthreads();
    {
        const int rrow = tid >> 3;
        const int rch = (tid & 7) * 64;
        const int rswz = (rrow & 7) << 4;
        u16* gp = C + (size_t)(r0 + rrow) * Nc + cb0 + (tid & 7) * 32;
        #pragma unroll
        for (int q = 0; q < 4; ++q) {
            uint4 dv = *(const uint4*)((const char*)Alds + rrow * 512 + ((rch + q * 16) ^ rswz));
            if (ACCUM) dv = addbf8(dv, oldv[q]);
            *(uint4*)(gp + q * 8) = dv;
        }
    }
}

// ============ weight convert+transpose ============
__global__ __launch_bounds__(256) void wcvt_k(const float* __restrict__ W,
    u16* __restrict__ Wt, int K, int N, int Kpad)
{
    int idx = blockIdx.x * 256 + threadIdx.x;
    if (idx >= N * Kpad) return;
    int n = idx / Kpad, kp = idx - n * Kpad;
    Wt[idx] = (kp < K) ? f2b(W[(size_t)kp * N + n]) : (u16)0;
}

__global__ void biaspack_k(const float* q, const float* k, const float* v, float* dst) {
    int t = threadIdx.x;
    dst[t] = q[t]; dst[256 + t] = k[t]; dst[512 + t] = v[t];
}

// ============ A_init bf16 [NB][192] ============
__global__ __launch_bounds__(256) void ainit_k(const float* __restrict__ fa,
    const float* __restrict__ fb, const int* __restrict__ b2a, u16* __restrict__ dst)
{
    const int w = threadIdx.x >> 6, l = threadIdx.x & 63;
    const int row = blockIdx.x * 4 + w;
    const int a = b2a[row];
    const float* fsrc = fa + (size_t)a * AFEAT;
    u16* d = dst + (size_t)row * KI_PAD;
    #pragma unroll
    for (int i = 0; i < 3; ++i) {
        int c = l + i * 64;
        float v;
        if (c < AFEAT) v = fsrc[c];
        else if (c < KINIT) v = fb[(size_t)row * BFEAT + (c - AFEAT)];
        else v = 0.f;
        d[c] = f2b(v);
    }
}

// ============ A_cat bf16 [NA][448] ============
__global__ __launch_bounds__(256) void acat_k(const float* __restrict__ fa,
    const u16* __restrict__ nei, u16* __restrict__ dst)
{
    const int w = threadIdx.x >> 6, l = threadIdx.x & 63;
    const int row = blockIdx.x * 4 + w;
    const float* fsrc = fa + (size_t)row * AFEAT;
    const u16* nsrc = nei + (size_t)row * H;
    u16* d = dst + (size_t)row * KO_PAD;
    #pragma unroll
    for (int i = 0; i < 7; ++i) {
        int c = l + i * 64;
        u16 v;
        if (c < AFEAT) v = f2b(fsrc[c]);
        else if (c < AFEAT + H) v = nsrc[c - AFEAT];
        else v = 0;
        d[c] = v;
    }
}

// ---------------- gather-sum ----------------
__global__ __launch_bounds__(256) void nei_sum_k(const u16* __restrict__ msg,
    const int* __restrict__ a2b, u16* __restrict__ nei)
{
    const int wave = threadIdx.x >> 6;
    const int lane = threadIdx.x & 63;
    const int atom = blockIdx.x * 4 + wave;
    float ax = 0.f, ay = 0.f, az = 0.f, aw = 0.f;
    #pragma unroll
    for (int j = 0; j < MAXNB; ++j) {
        int b = a2b[atom * MAXNB + j];
        ushort4 v = *(const ushort4*)(msg + (size_t)b * H + lane * 4);
        ax += b2f(v.x); ay += b2f(v.y); az += b2f(v.z); aw += b2f(v.w);
    }
    *(ushort4*)(nei + (size_t)atom * H + lane * 4) = f2b4(ax, ay, az, aw);
}

// ---------------- per-row LN (ln_atom only) ----------------
__global__ __launch_bounds__(256) void row_ln_k(const u16* __restrict__ in,
    u16* __restrict__ out, const float* __restrict__ s, const float* __restrict__ b)
{
    const int wave = threadIdx.x >> 6;
    const int lane = threadIdx.x & 63;
    const int row = blockIdx.x * 4 + wave;
    ushort4 u = *(const ushort4*)(in + (size_t)row * H + lane * 4);
    float vx = b2f(u.x), vy = b2f(u.y), vz = b2f(u.z), vw = b2f(u.w);
    float mean = wave_sum(vx + vy + vz + vw) * (1.0f / H);
    float dx = vx - mean, dy = vy - mean, dz = vz - mean, dw = vw - mean;
    float var = wave_sum(dx * dx + dy * dy + dz * dz + dw * dw) * (1.0f / H);
    float inv = rsqrtf(var + EPSLN);
    float4 s4 = *(const float4*)(s + lane * 4);
    float4 b4 = *(const float4*)(b + lane * 4);
    *(ushort4*)(out + (size_t)row * H + lane * 4) =
        f2b4(dx * inv * s4.x + b4.x, dy * inv * s4.y + b4.y,
             dz * inv * s4.z + b4.z, dw * inv * s4.w + b4.w);
}

// ============== MFMA attention: 1 block/mol, 1 wave/head ==============
#define VPAD 268
__global__ __launch_bounds__(256) void attn_mfma_k(const u16* __restrict__ qkv,
    u16* __restrict__ ctx)
{
    __shared__ u16 Vs[48][VPAD];
    const int mol = blockIdx.x;
    const int tid = threadIdx.x;
    const int w = tid >> 6;
    const int l = tid & 63;
    const int fr = l & 15;
    const int fh = l >> 4;
    const size_t qb = (size_t)mol * APM * 768;

    {
        const int r = tid >> 4;
        const int c = (tid & 15) * 16;
        #pragma unroll
        for (int i = 0; i < 3; ++i) {
            const int row = r + i * 16;
            const u16* src = qkv + qb + (size_t)row * 768 + 512 + c;
            ushort4 a0 = *(const ushort4*)(src);
            ushort4 a1 = *(const ushort4*)(src + 4);
            ushort4 a2 = *(const ushort4*)(src + 8);
            ushort4 a3 = *(const ushort4*)(src + 12);
            *(ushort4*)&Vs[row][c]      = a0;
            *(ushort4*)&Vs[row][c + 4]  = a1;
            *(ushort4*)&Vs[row][c + 8]  = a2;
            *(ushort4*)&Vs[row][c + 12] = a3;
        }
    }
    __syncthreads();

    f32x4 st[3][3];
    {
        bf16x8 kf[3][2], qf[3][2];
        #pragma unroll
        for (int t = 0; t < 3; ++t)
            #pragma unroll
            for (int ks = 0; ks < 2; ++ks) {
                const size_t rowb = qb + (size_t)(t * 16 + fr) * 768;
                kf[t][ks] = *(const bf16x8*)(qkv + rowb + 256 + w * 64 + ks * 32 + fh * 8);
                qf[t][ks] = *(const bf16x8*)(qkv + rowb +       w * 64 + ks * 32 + fh * 8);
            }
        #pragma unroll
        for (int mi = 0; mi < 3; ++mi)
            #pragma unroll
            for (int ni = 0; ni < 3; ++ni) {
                f32x4 a = (f32x4){0.f, 0.f, 0.f, 0.f};
                a = __builtin_amdgcn_mfma_f32_16x16x32_bf16(kf[mi][0], qf[ni][0], a, 0, 0, 0);
                a = __builtin_amdgcn_mfma_f32_16x16x32_bf16(kf[mi][1], qf[ni][1], a, 0, 0, 0);
                st[mi][ni] = a;
            }
    }

    float inv_sum[3];
    #pragma unroll
    for (int ni = 0; ni < 3; ++ni) {
        float m = -1e30f;
        #pragma unroll
        for (int mi = 0; mi < 3; ++mi)
            #pragma unroll
            for (int j = 0; j < 4; ++j) m = fmaxf(m, st[mi][ni][j]);
        m = fmaxf(m, __shfl_xor(m, 16));
        m = fmaxf(m, __shfl_xor(m, 32));
        float s = 0.f;
        #pragma unroll
        for (int mi = 0; mi < 3; ++mi)
            #pragma unroll
            for (int j = 0; j < 4; ++j) {
                float e = __expf((st[mi][ni][j] - m) * 0.125f);
                st[mi][ni][j] = e;
                s += e;
            }
        s += __shfl_xor(s, 16);
        s += __shfl_xor(s, 32);
        inv_sum[ni] = 1.0f / s;
    }

    bf16x4 pf[3][3];
    #pragma unroll
    for (int mi = 0; mi < 3; ++mi)
        #pragma unroll
        for (int ni = 0; ni < 3; ++ni) {
            bf16x4 p;
            p[0] = (short)f2b(st[mi][ni][0]);
            p[1] = (short)f2b(st[mi][ni][1]);
            p[2] = (short)f2b(st[mi][ni][2]);
            p[3] = (short)f2b(st[mi][ni][3]);
            pf[mi][ni] = p;
        }

    f32x4 co[4][3];
    #pragma unroll
    for (int dt = 0; dt < 4; ++dt)
        #pragma unroll
        for (int ni = 0; ni < 3; ++ni) co[dt][ni] = (f32x4){0.f, 0.f, 0.f, 0.f};
    #pragma unroll
    for (int kt = 0; kt < 3; ++kt) {
        bf16x4 vf[4];
        #pragma unroll
        for (int dt = 0; dt < 4; ++dt) {
            const int colu = w * 64 + dt * 16 + fr;
            bf16x4 t;
            #pragma unroll
            for (int e = 0; e < 4; ++e)
                t[e] = (short)Vs[kt * 16 + fh * 4 + e][colu];
            vf[dt] = t;
        }
        #pragma unroll
        for (int dt = 0; dt < 4; ++dt)
            #pragma unroll
            for (int ni = 0; ni < 3; ++ni)
                co[dt][ni] = mfma16(vf[dt], pf[kt][ni], co[dt][ni]);
    }

    #pragma unroll
    for (int ni = 0; ni < 3; ++ni) {
        const float is = inv_sum[ni];
        u16* rowp = ctx + (size_t)(mol * APM + ni * 16 + fr) * H + w * 64;
        #pragma unroll
        for (int dt = 0; dt < 4; ++dt) {
            *(ushort4*)(rowp + dt * 16 + fh * 4) =
                f2b4(co[dt][ni][0] * is, co[dt][ni][1] * is,
                     co[dt][ni][2] * is, co[dt][ni][3] * is);
        }
    }
}

// ---------------- readout prep ----------------
__global__ __launch_bounds__(256) void readout_prep_k(const float* __restrict__ rk_w,
    const float* __restrict__ rk_b, const float* __restrict__ query, float* __restrict__ small)
{
    __shared__ float qsh[256];
    __shared__ float red[4];
    const int t = threadIdx.x;
    qsh[t] = query[t];
    __syncthreads();
    float acc = 0.f;
    #pragma unroll
    for (int c = 0; c < 256; c += 4) {
        float4 w = *(const float4*)&rk_w[(size_t)t * 256 + c];
        acc += w.x * qsh[c] + w.y * qsh[c+1] + w.z * qsh[c+2] + w.w * qsh[c+3];
    }
    small[t] = acc;
    float term = wave_sum(rk_b[t] * qsh[t]);
    if ((t & 63) == 0) red[t >> 6] = term;
    __syncthreads();
    if (t == 0) small[256] = red[0] + red[1] + red[2] + red[3];
}

// ---------------- readout ----------------
__global__ __launch_bounds__(256) void readout_k(const u16* __restrict__ x,
    const float* __restrict__ small, float* __restrict__ out)
{
    __shared__ float sc[48];
    __shared__ float rvs[256];
    const int mol = blockIdx.x;
    const int t = threadIdx.x;
    const int wave = t >> 6, lane = t & 63;
    rvs[t] = small[t];
    __syncthreads();
    const float c0 = small[256];
    const size_t xb = (size_t)mol * APM * H;
    for (int i = 0; i < 12; ++i) {
        int s = wave * 12 + i;
        ushort4 xu = *(const ushort4*)(x + xb + (size_t)s * H + lane * 4);
        float dot = b2f(xu.x) * rvs[lane*4] + b2f(xu.y) * rvs[lane*4+1]
                  + b2f(xu.z) * rvs[lane*4+2] + b2f(xu.w) * rvs[lane*4+3];
        dot = wave_sum(dot);
        if (lane == 0) sc[s] = dot + c0;
    }
    __syncthreads();
    if (wave == 0) {
        float v = (lane < 48) ? sc[lane] : -1e30f;
        float mx = v;
        #pragma unroll
        for (int m = 1; m < 64; m <<= 1) mx = fmaxf(mx, __shfl_xor(mx, m));
        float e = (lane < 48) ? __expf(v - mx) : 0.f;
        float sum = wave_sum(e);
        if (lane < 48) sc[lane] = e / sum;
    }
    __syncthreads();
    float acc = 0.f;
    for (int s = 0; s < 48; ++s) acc += sc[s] * b2f(x[xb + (size_t)s * H + t]);
    out[(size_t)mol * H + t] = acc;
}

__global__ void diag_k(float* out, int n, float val) {
    int i = blockIdx.x * 256 + threadIdx.x;
    if (i < n) out[i] = (i == 0) ? val : 0.f;
}

extern "C" void kernel_launch(void* const* d_in, const int* in_sizes, int n_in,
                              void* d_out, int out_size, void* d_ws, size_t ws_size,
                              hipStream_t stream)
{
    const float* f_atoms = (const float*)d_in[0];
    const float* f_bonds = (const float*)d_in[1];
    const int*   a2b     = (const int*)d_in[2];
    const int*   b2a     = (const int*)d_in[3];
    const int*   b2revb  = (const int*)d_in[4];
    const float* W_i = (const float*)d_in[5];
    const float* b_i = (const float*)d_in[6];
    const float* W_h = (const float*)d_in[7];
    const float* b_h = (const float*)d_in[8];
    const float* ln_msg_s = (const float*)d_in[9];
    const float* ln_msg_b = (const float*)d_in[10];
    const float* W_o = (const float*)d_in[11];
    const float* b_o = (const float*)d_in[12];
    const float* ln_atom_s = (const float*)d_in[13];
    const float* ln_atom_b = (const float*)d_in[14];
    const float* q_w = (const float*)d_in[15];
    const float* q_b = (const float*)d_in[16];
    const float* k_w = (const float*)d_in[17];
    const float* k_b = (const float*)d_in[18];
    const float* v_w = (const float*)d_in[19];
    const float* v_b = (const float*)d_in[20];
    const float* o_w = (const float*)d_in[21];
    const float* o_b = (const float*)d_in[22];
    const float* ln1_s = (const float*)d_in[23];
    const float* ln1_b = (const float*)d_in[24];
    const float* ln2_s = (const float*)d_in[25];
    const float* ln2_b = (const float*)d_in[26];
    const float* ff1_w = (const float*)d_in[27];
    const float* ff1_b = (const float*)d_in[28];
    const float* ff2_w = (const float*)d_in[29];
    const float* ff2_b = (const float*)d_in[30];
    const float* rquery = (const float*)d_in[31];
    const float* rk_w = (const float*)d_in[32];
    const float* rk_b = (const float*)d_in[33];

    const size_t SZ_MSG = (size_t)NB * H;
    const size_t SZ_NEI = (size_t)NA * H;
    const size_t W_I_SZ  = 256 * KI_PAD;
    const size_t W_H_SZ  = 3 * 256 * 256;
    const size_t W_O_SZ  = 256 * KO_PAD;
    const size_t W_QKV_SZ = 768 * 256;
    const size_t W_OG_SZ = 256 * 256;
    const size_t W_F1_SZ = 512 * 256;
    const size_t W_F2_SZ = 256 * 512;
    const size_t wtotal = W_I_SZ + W_H_SZ + W_O_SZ + W_QKV_SZ + W_OG_SZ + W_F1_SZ + W_F2_SZ;
    const size_t required = (2 * SZ_MSG + SZ_NEI + wtotal) * 2 + 768 * 4 + 257 * 4 + 256;
    if (ws_size < required) {
        diag_k<<<dim3((out_size + 255) / 256), dim3(256), 0, stream>>>(
            (float*)d_out, out_size, (float)(ws_size >> 20));
        return;
    }

    u16* msgA   = (u16*)d_ws;
    u16* msgB   = msgA + SZ_MSG;
    u16* nei    = msgB + SZ_MSG;
    u16* wt_i   = nei + SZ_NEI;
    u16* wt_h   = wt_i + W_I_SZ;
    u16* wt_o   = wt_h + W_H_SZ;
    u16* wt_qkv = wt_o + W_O_SZ;
    u16* wt_og  = wt_qkv + W_QKV_SZ;
    u16* wt_f1  = wt_og + W_OG_SZ;
    u16* wt_f2  = wt_f1 + W_F1_SZ;
    float* qkvb = (float*)(wt_f2 + W_F2_SZ);
    float* small = qkvb + 768;
    float* out = (float*)d_out;

    dim3 blk(256);
    dim3 blk5(512);
    #define WCVT(W, DST, K, N, KP) wcvt_k<<<dim3(((N)*(KP)+255)/256), blk, 0, stream>>>(W, DST, K, N, KP)

    WCVT(W_i, wt_i, KINIT, 256, KI_PAD);
    WCVT(W_h,           wt_h,           256, 256, 256);
    WCVT(W_h + 65536,   wt_h + 65536,   256, 256, 256);
    WCVT(W_h + 131072,  wt_h + 131072,  256, 256, 256);
    WCVT(W_o, wt_o, AFEAT + H, 256, KO_PAD);
    WCVT(q_w, wt_qkv,          256, 256, 256);
    WCVT(k_w, wt_qkv + 65536,  256, 256, 256);
    WCVT(v_w, wt_qkv + 131072, 256, 256, 256);
    WCVT(o_w, wt_og, 256, 256, 256);
    WCVT(ff1_w, wt_f1, 256, 512, 256);
    WCVT(ff2_w, wt_f2, 512, 256, 512);
    biaspack_k<<<dim3(1), blk, 0, stream>>>(q_b, k_b, v_b, qkvb);

    // ---- 1. init message GEMM ----
    ainit_k<<<dim3(NB / 4), blk, 0, stream>>>(f_atoms, f_bonds, b2a, msgB);
    gemm_mfma_k<true, false><<<dim3(NB / 128, 2), blk, 0, stream>>>(
        msgB, KI_PAD, wt_i, b_i, msgA, H, KI_PAD);

    // ---- 2. depth loop: fused gather+LN+GEMM, ping-pong msg ----
    u16* cur = msgA;
    u16* oth = msgB;
    for (int t = 0; t < 3; ++t) {
        nei_sum_k<<<dim3(NA / 4), blk, 0, stream>>>(cur, a2b, nei);
        fln_gemm_k<LGather, true, true><<<dim3(NB / 64, 1), blk5, 0, stream>>>(
            LGather{nei, cur, b2a, b2revb}, wt_h + (size_t)t * 65536,
            ln_msg_s + t * H, ln_msg_b + t * H, b_h + t * H,
            cur, oth, H);
        u16* tmp = cur; cur = oth; oth = tmp;
    }

    // ---- 3. atom hidden ----
    nei_sum_k<<<dim3(NA / 4), blk, 0, stream>>>(cur, a2b, nei);
    acat_k<<<dim3(NA / 4), blk, 0, stream>>>(f_atoms, nei, oth);
    u16* x = cur;
    gemm_mfma_k<true, false><<<dim3(NA / 128, 2), blk, 0, stream>>>(
        oth, KO_PAD, wt_o, b_o, x, H, KO_PAD);
    row_ln_k<<<dim3(NA / 4), blk, 0, stream>>>(x, x, ln_atom_s, ln_atom_b);

    // ---- 4. transformer layer ----
    u16* qkv = oth;
    fln_gemm_k<LPlain, false, false><<<dim3(NA / 64, 3), blk5, 0, stream>>>(
        LPlain{x}, wt_qkv, ln1_s, ln1_b, qkvb, x, qkv, 768);
    u16* ctx = nei;
    attn_mfma_k<<<dim3(NMOL), blk, 0, stream>>>(qkv, ctx);
    gemm_mfma_k<false, true><<<dim3(NA / 128, 2), blk, 0, stream>>>(
        ctx, H, wt_og, o_b, x, H, H);
    u16* ff1o = oth;
    fln_gemm_k<LPlain, true, false><<<dim3(NA / 64, 2), blk5, 0, stream>>>(
        LPlain{x}, wt_f1, ln2_s, ln2_b, ff1_b, x, ff1o, 512);
    gemm_mfma_k<false, true><<<dim3(NA / 128, 2), blk, 0, stream>>>(
        ff1o, 512, wt_f2, ff2_b, x, H, 512);

    // ---- 5. readout ----
    readout_prep_k<<<dim3(1), blk, 0, stream>>>(rk_w, rk_b, rquery, small);
    readout_k<<<dim3(NMOL), blk, 0, stream>>>(x, small, out);
}